// Round 1
// baseline (4630.369 us; speedup 1.0000x reference)
//
#include <hip/hip_runtime.h>

#define DEV __device__ __forceinline__

// ---------- exact (non-contracted) squared distance: matches jnp sum(((a-b)**2), -1) ----------
DEV float d2_exact(float ax, float ay, float az, float bx, float by, float bz) {
    float dx = __fadd_rn(ax, -bx);
    float dy = __fadd_rn(ay, -by);
    float dz = __fadd_rn(az, -bz);
    return __fadd_rn(__fadd_rn(__fmul_rn(dx, dx), __fmul_rn(dy, dy)), __fmul_rn(dz, dz));
}

DEV unsigned long long umax64(unsigned long long a, unsigned long long b) { return a > b ? a : b; }
DEV unsigned long long umin64(unsigned long long a, unsigned long long b) { return a < b ? a : b; }

// =====================================================================================
// FPS: one block per batch. pos [B,N,3] -> pos_out [B,S,3]. Deterministic start idx 0.
// argmax tie -> lowest index (matches jnp.argmax) via key = (f32bits << 32) | ~idx.
// =====================================================================================
template <int N, int S, int T>
__global__ __launch_bounds__(T) void fps_kernel(const float* __restrict__ pos,
                                                float* __restrict__ pos_out) {
    constexpr int C  = N / T;
    constexpr int NW = T / 64;
    __shared__ float sx[N], sy[N], sz[N];
    __shared__ unsigned long long sred[NW];
    __shared__ int scur;
    const int b = blockIdx.x, t = threadIdx.x;
    const float* p = pos + (size_t)b * N * 3;
    for (int i = t; i < N; i += T) { sx[i] = p[3*i]; sy[i] = p[3*i+1]; sz[i] = p[3*i+2]; }
    __syncthreads();
    float px[C], py[C], pz[C], md[C];
    const int base = t * C;
#pragma unroll
    for (int i = 0; i < C; i++) { px[i]=sx[base+i]; py[i]=sy[base+i]; pz[i]=sz[base+i]; md[i]=1e30f; }
    float cx = sx[0], cy = sy[0], cz = sz[0];
    const int lane = t & 63, wave = t >> 6;
    for (int s = 0; s < S; s++) {
        if (t == 0) {
            float* po = pos_out + ((size_t)b * S + s) * 3;
            po[0] = cx; po[1] = cy; po[2] = cz;
        }
        float bv = -1.0f; int bi = 0;
#pragma unroll
        for (int i = 0; i < C; i++) {
            float d = d2_exact(px[i], py[i], pz[i], cx, cy, cz);
            float m = fminf(md[i], d);
            md[i] = m;
            if (m > bv) { bv = m; bi = base + i; }   // strict > keeps first max in chunk
        }
        unsigned long long key =
            ((unsigned long long)__float_as_uint(bv) << 32) | (unsigned long long)(unsigned int)(~bi);
#pragma unroll
        for (int o = 32; o >= 1; o >>= 1) key = umax64(key, __shfl_xor(key, o, 64));
        if (lane == 0) sred[wave] = key;
        __syncthreads();
        if (wave == 0) {
            unsigned long long v = (lane < NW) ? sred[lane] : 0ULL;
#pragma unroll
            for (int o = 8; o >= 1; o >>= 1) v = umax64(v, __shfl_xor(v, o, 64));
            if (lane == 0) scur = (int)(~(unsigned int)v);
        }
        __syncthreads();
        const int cur = scur;
        cx = sx[cur]; cy = sy[cur]; cz = sz[cur];
    }
}

// =====================================================================================
// Ball query: one block per (b,s). Emits the neighbor SET (order-free when count<=K,
// exact top-K extraction with lowest-index ties when count>K).
// =====================================================================================
template <int NSRC, int T>
__global__ __launch_bounds__(T) void ballq_kernel(const float* __restrict__ pos_src,
                                                  const float* __restrict__ pos_dst,
                                                  const int S, const float rsq,
                                                  int* __restrict__ nidx, int* __restrict__ ncnt) {
    __shared__ float d2s[NSRC];
    __shared__ int scnt, sfill;
    __shared__ unsigned long long sred[T / 64];
    const int bs = blockIdx.x, t = threadIdx.x;
    const int b = bs / S;
    const float* pd = pos_dst + (size_t)bs * 3;
    const float qx = pd[0], qy = pd[1], qz = pd[2];
    const float* ps = pos_src + (size_t)b * NSRC * 3;
    if (t == 0) { scnt = 0; sfill = 0; }
    __syncthreads();
    int lc = 0;
    for (int j = t; j < NSRC; j += T) {
        float d2 = d2_exact(ps[3*j], ps[3*j+1], ps[3*j+2], qx, qy, qz);
        d2s[j] = d2;
        lc += (d2 < rsq) ? 1 : 0;
    }
    if (lc) atomicAdd(&scnt, lc);
    __syncthreads();
    const int c = scnt;
    int* mi = nidx + (size_t)bs * 64;
    if (c <= 64) {
        if (t == 0) ncnt[bs] = c;
        for (int j = t; j < NSRC; j += T) {
            if (d2s[j] < rsq) { int p = atomicAdd(&sfill, 1); mi[p] = j; }
        }
    } else {
        if (t == 0) ncnt[bs] = 64;
        const int lane = t & 63, wave = t >> 6;
        for (int k = 0; k < 64; k++) {
            unsigned long long best = ~0ULL;
            for (int j = t; j < NSRC; j += T) {
                unsigned long long key =
                    ((unsigned long long)__float_as_uint(d2s[j]) << 32) | (unsigned int)j;
                best = umin64(best, key);
            }
#pragma unroll
            for (int o = 32; o >= 1; o >>= 1) best = umin64(best, __shfl_xor(best, o, 64));
            if (lane == 0) sred[wave] = best;
            __syncthreads();
            if (t == 0) {
                unsigned long long v = sred[0];
                for (int w = 1; w < T / 64; w++) v = umin64(v, sred[w]);
                int j = (int)(unsigned int)v;
                mi[k] = j;
                d2s[j] = __uint_as_float(0x7F800000u);  // +inf: exclude from later picks
            }
            __syncthreads();
        }
    }
}

// =====================================================================================
// Per-dst GEMM helpers. Activations live transposed in LDS: inT[ci][k], row stride 68
// floats (float4-aligned, bank-spread). Block = 256 threads; thread = (tc=t&15, tr=t>>4)
// owns 4 rows x 4 cols of the 64x64 output tile.
// =====================================================================================
#define LP 68

template <int CIN, int COUT, bool RELU>
DEV void gemm_tile(const float* __restrict__ inT, const float* __restrict__ W,
                   const float* __restrict__ bias, float* __restrict__ outT,
                   float (*wt)[64], const int t) {
    const int tc = t & 15, tr = t >> 4;
    for (int co0 = 0; co0 < COUT; co0 += 64) {
        float acc[4][4] = {};
        for (int ci0 = 0; ci0 < CIN; ci0 += 32) {
            const int cc = (CIN - ci0) < 32 ? (CIN - ci0) : 32;
            __syncthreads();
            for (int e = t; e < cc * 64; e += 256) {
                const int co = e & 63, ci = e >> 6;
                wt[ci][co] = W[(size_t)(ci0 + ci) * COUT + co0 + co];
            }
            __syncthreads();
            for (int ci = 0; ci < cc; ci++) {
                const float4 a = *(const float4*)(inT + (size_t)(ci0 + ci) * LP + 4 * tr);
                const float4 w = *(const float4*)(&wt[ci][4 * tc]);
                const float av[4] = {a.x, a.y, a.z, a.w};
                const float wv[4] = {w.x, w.y, w.z, w.w};
#pragma unroll
                for (int i = 0; i < 4; i++)
#pragma unroll
                    for (int j = 0; j < 4; j++) acc[i][j] = fmaf(av[i], wv[j], acc[i][j]);
            }
        }
#pragma unroll
        for (int j = 0; j < 4; j++) {
            const float bj = bias[co0 + 4 * tc + j];
            float4 o;
            o.x = acc[0][j] + bj; o.y = acc[1][j] + bj; o.z = acc[2][j] + bj; o.w = acc[3][j] + bj;
            if (RELU) {
                o.x = fmaxf(o.x, 0.f); o.y = fmaxf(o.y, 0.f);
                o.z = fmaxf(o.z, 0.f); o.w = fmaxf(o.w, 0.f);
            }
            *(float4*)(outT + (size_t)(co0 + 4 * tc + j) * LP + 4 * tr) = o;
        }
    }
}

template <int CIN, int COUT>
DEV void gemm_maxout(const float* __restrict__ inT, const float* __restrict__ W,
                     const float* __restrict__ bias, float* __restrict__ outg,
                     float (*wt)[64], float (*colred)[64], const int t, const int c) {
    const int tc = t & 15, tr = t >> 4, wave = t >> 6;
    for (int co0 = 0; co0 < COUT; co0 += 64) {
        float acc[4][4] = {};
        for (int ci0 = 0; ci0 < CIN; ci0 += 32) {
            const int cc = (CIN - ci0) < 32 ? (CIN - ci0) : 32;
            __syncthreads();
            for (int e = t; e < cc * 64; e += 256) {
                const int co = e & 63, ci = e >> 6;
                wt[ci][co] = W[(size_t)(ci0 + ci) * COUT + co0 + co];
            }
            __syncthreads();
            for (int ci = 0; ci < cc; ci++) {
                const float4 a = *(const float4*)(inT + (size_t)(ci0 + ci) * LP + 4 * tr);
                const float4 w = *(const float4*)(&wt[ci][4 * tc]);
                const float av[4] = {a.x, a.y, a.z, a.w};
                const float wv[4] = {w.x, w.y, w.z, w.w};
#pragma unroll
                for (int i = 0; i < 4; i++)
#pragma unroll
                    for (int j = 0; j < 4; j++) acc[i][j] = fmaf(av[i], wv[j], acc[i][j]);
            }
        }
        float vr[4];
#pragma unroll
        for (int j = 0; j < 4; j++) {
            const float bj = bias[co0 + 4 * tc + j];
            float m = -1e30f;  // same sentinel as reference mask
#pragma unroll
            for (int i = 0; i < 4; i++) {
                const float v = acc[i][j] + bj;
                if (4 * tr + i < c) m = fmaxf(m, v);
            }
            m = fmaxf(m, __shfl_xor(m, 16, 64));
            m = fmaxf(m, __shfl_xor(m, 32, 64));
            vr[j] = m;
        }
        if ((t & 48) == 0) {
#pragma unroll
            for (int j = 0; j < 4; j++) colred[wave][4 * tc + j] = vr[j];
        }
        __syncthreads();
        if (t < 64) {
            const float m = fmaxf(fmaxf(colred[0][t], colred[1][t]),
                                  fmaxf(colred[2][t], colred[3][t]));
            outg[co0 + t] = m;
        }
        __syncthreads();
    }
}

// =====================================================================================
// SA conv: one block per dst point. Gathers (x_j, rel) into LDS (rows>=count zeroed),
// 3-layer MLP, masked max over neighbors -> x_out[bs].
// =====================================================================================
template <int CX, int C0, int C1, int C2, int NSRC>
__global__ __launch_bounds__(256) void sa_conv_kernel(
    const float* __restrict__ x_src, const float* __restrict__ pos_src,
    const float* __restrict__ pos_dst, const int* __restrict__ nidx,
    const int* __restrict__ ncnt,
    const float* __restrict__ w0, const float* __restrict__ b0,
    const float* __restrict__ w1, const float* __restrict__ b1,
    const float* __restrict__ w2, const float* __restrict__ b2,
    float* __restrict__ x_out, const int S) {
    constexpr int CIN = CX + 3;
    constexpr int AR  = (CIN > C1) ? CIN : C1;
    __shared__ float bufA[AR * LP];
    __shared__ float bufB[C0 * LP];
    __shared__ float wt[32][64];
    __shared__ float colred[4][64];
    const int bs = blockIdx.x, t = threadIdx.x;
    const int b = bs / S;
    const int c = ncnt[bs];
    const int* ni = nidx + (size_t)bs * 64;
    const float* pd = pos_dst + (size_t)bs * 3;
    const float qx = pd[0], qy = pd[1], qz = pd[2];
    if constexpr (CX > 0) {
        constexpr int LG = (CX == 256) ? 8 : 7;
        for (int e = t; e < 64 * CX; e += 256) {
            const int ci = e & (CX - 1), k = e >> LG;
            float v = 0.f;
            if (k < c) v = x_src[((size_t)b * NSRC + ni[k]) * CX + ci];
            bufA[(size_t)ci * LP + k] = v;
        }
    }
    for (int e = t; e < 192; e += 256) {
        const int k = e & 63, ci = e >> 6;
        float v = 0.f;
        if (k < c) {
            const float* pj = pos_src + ((size_t)b * NSRC + ni[k]) * 3;
            v = (ci == 0 ? pj[0] - qx : (ci == 1 ? pj[1] - qy : pj[2] - qz));
        }
        bufA[(size_t)(CX + ci) * LP + k] = v;
    }
    __syncthreads();
    gemm_tile<CIN, C0, true>(bufA, w0, b0, bufB, wt, t);
    __syncthreads();
    gemm_tile<C0, C1, true>(bufB, w1, b1, bufA, wt, t);
    __syncthreads();
    gemm_maxout<C1, C2>(bufA, w2, b2, x_out + (size_t)bs * C2, wt, colred, t, c);
}

// =====================================================================================
// Global SA: layer 1 (515 -> 512, relu) to ws, layer 2 (512 -> 1024) + max over 64 pts.
// =====================================================================================
__global__ __launch_bounds__(256) void gsa1_kernel(const float* __restrict__ x3,
                                                   const float* __restrict__ pos3,
                                                   const float* __restrict__ w0,
                                                   const float* __restrict__ b0,
                                                   float* __restrict__ h1) {
    __shared__ float at[32][LP];
    __shared__ float wt[32][64];
    const int b = blockIdx.x >> 3, co0 = (blockIdx.x & 7) * 64;
    const int t = threadIdx.x, tc = t & 15, tr = t >> 4;
    float acc[4][4] = {};
    for (int ci0 = 0; ci0 < 515; ci0 += 32) {
        const int cc = (515 - ci0) < 32 ? (515 - ci0) : 32;
        __syncthreads();
        for (int e = t; e < cc * 64; e += 256) {
            const int k = e & 63, ci = e >> 6, cig = ci0 + ci;
            at[ci][k] = (cig < 512) ? x3[((size_t)b * 64 + k) * 512 + cig]
                                    : pos3[((size_t)b * 64 + k) * 3 + (cig - 512)];
        }
        for (int e = t; e < cc * 64; e += 256) {
            const int co = e & 63, ci = e >> 6;
            wt[ci][co] = w0[(size_t)(ci0 + ci) * 512 + co0 + co];
        }
        __syncthreads();
        for (int ci = 0; ci < cc; ci++) {
            const float4 a = *(const float4*)&at[ci][4 * tr];
            const float4 w = *(const float4*)&wt[ci][4 * tc];
            const float av[4] = {a.x, a.y, a.z, a.w};
            const float wv[4] = {w.x, w.y, w.z, w.w};
#pragma unroll
            for (int i = 0; i < 4; i++)
#pragma unroll
                for (int j = 0; j < 4; j++) acc[i][j] = fmaf(av[i], wv[j], acc[i][j]);
        }
    }
#pragma unroll
    for (int j = 0; j < 4; j++) {
        const float bj = b0[co0 + 4 * tc + j];
#pragma unroll
        for (int i = 0; i < 4; i++) {
            float v = acc[i][j] + bj;
            v = fmaxf(v, 0.f);
            h1[((size_t)b * 64 + 4 * tr + i) * 512 + co0 + 4 * tc + j] = v;
        }
    }
}

__global__ __launch_bounds__(256) void gsa2_kernel(const float* __restrict__ h1,
                                                   const float* __restrict__ w1,
                                                   const float* __restrict__ b1,
                                                   float* __restrict__ out) {
    __shared__ float at[32][LP];
    __shared__ float wt[32][64];
    __shared__ float colred[4][64];
    const int b = blockIdx.x >> 4, co0 = (blockIdx.x & 15) * 64;
    const int t = threadIdx.x, tc = t & 15, tr = t >> 4, wave = t >> 6;
    float acc[4][4] = {};
    for (int ci0 = 0; ci0 < 512; ci0 += 32) {
        __syncthreads();
        for (int e = t; e < 32 * 64; e += 256) {
            const int k = e & 63, ci = e >> 6;
            at[ci][k] = h1[((size_t)b * 64 + k) * 512 + ci0 + ci];
        }
        for (int e = t; e < 32 * 64; e += 256) {
            const int co = e & 63, ci = e >> 6;
            wt[ci][co] = w1[(size_t)(ci0 + ci) * 1024 + co0 + co];
        }
        __syncthreads();
        for (int ci = 0; ci < 32; ci++) {
            const float4 a = *(const float4*)&at[ci][4 * tr];
            const float4 w = *(const float4*)&wt[ci][4 * tc];
            const float av[4] = {a.x, a.y, a.z, a.w};
            const float wv[4] = {w.x, w.y, w.z, w.w};
#pragma unroll
            for (int i = 0; i < 4; i++)
#pragma unroll
                for (int j = 0; j < 4; j++) acc[i][j] = fmaf(av[i], wv[j], acc[i][j]);
        }
    }
    float vr[4];
#pragma unroll
    for (int j = 0; j < 4; j++) {
        const float bj = b1[co0 + 4 * tc + j];
        float m = -1e30f;
#pragma unroll
        for (int i = 0; i < 4; i++) m = fmaxf(m, acc[i][j] + bj);
        m = fmaxf(m, __shfl_xor(m, 16, 64));
        m = fmaxf(m, __shfl_xor(m, 32, 64));
        vr[j] = m;
    }
    if ((t & 48) == 0) {
#pragma unroll
        for (int j = 0; j < 4; j++) colred[wave][4 * tc + j] = vr[j];
    }
    __syncthreads();
    if (t < 64) {
        const float m = fmaxf(fmaxf(colred[0][t], colred[1][t]),
                              fmaxf(colred[2][t], colred[3][t]));
        out[(size_t)b * 1024 + co0 + t] = m;
    }
}

// =====================================================================================
extern "C" void kernel_launch(void* const* d_in, const int* in_sizes, int n_in,
                              void* d_out, int out_size, void* d_ws, size_t ws_size,
                              hipStream_t stream) {
    (void)in_sizes; (void)n_in; (void)out_size; (void)ws_size;
    const float* pos    = (const float*)d_in[0];
    const float* sa1_w0 = (const float*)d_in[1];  const float* sa1_b0 = (const float*)d_in[2];
    const float* sa1_w1 = (const float*)d_in[3];  const float* sa1_b1 = (const float*)d_in[4];
    const float* sa1_w2 = (const float*)d_in[5];  const float* sa1_b2 = (const float*)d_in[6];
    const float* sa2_w0 = (const float*)d_in[7];  const float* sa2_b0 = (const float*)d_in[8];
    const float* sa2_w1 = (const float*)d_in[9];  const float* sa2_b1 = (const float*)d_in[10];
    const float* sa2_w2 = (const float*)d_in[11]; const float* sa2_b2 = (const float*)d_in[12];
    const float* sa3_w0 = (const float*)d_in[13]; const float* sa3_b0 = (const float*)d_in[14];
    const float* sa3_w1 = (const float*)d_in[15]; const float* sa3_b1 = (const float*)d_in[16];
    const float* sa3_w2 = (const float*)d_in[17]; const float* sa3_b2 = (const float*)d_in[18];
    const float* sa4_w0 = (const float*)d_in[19]; const float* sa4_b0 = (const float*)d_in[20];
    const float* sa4_w1 = (const float*)d_in[21]; const float* sa4_b1 = (const float*)d_in[22];
    float* out = (float*)d_out;
    char* ws = (char*)d_ws;

    float* pos1 = (float*)(ws + 0);         // [8,1024,3]
    float* pos2 = (float*)(ws + 98304);     // [8,256,3]
    float* pos3 = (float*)(ws + 122880);    // [8,64,3]
    float* x1   = (float*)(ws + 129024);    // [8,1024,128]
    float* x2   = (float*)(ws + 4323328);   // [8,256,256]
    float* x3   = (float*)(ws + 6420480);   // [8,64,512]
    int* nidx1  = (int*)(ws + 7469056);     // [8*1024,64]
    int* ncnt1  = (int*)(ws + 9566208);     // [8*1024]
    int* nidx2  = (int*)(ws + 9598976);     // [8*256,64]
    int* ncnt2  = (int*)(ws + 10123264);    // [8*256]
    int* nidx3  = (int*)(ws + 10131456);    // [8*64,64]
    int* ncnt3  = (int*)(ws + 10262528);    // [8*64]
    float* h1g  = (float*)(ws + 10264576);  // [8*64,512]

    const float rsq1 = (float)(0.2 * 0.2);
    const float rsq2 = (float)(0.4 * 0.4);
    const float rsq3 = (float)(0.8 * 0.8);

    fps_kernel<4096, 1024, 1024><<<dim3(8), dim3(1024), 0, stream>>>(pos, pos1);
    fps_kernel<1024, 256, 256><<<dim3(8), dim3(256), 0, stream>>>(pos1, pos2);
    fps_kernel<256, 64, 256><<<dim3(8), dim3(256), 0, stream>>>(pos2, pos3);

    ballq_kernel<4096, 256><<<dim3(8 * 1024), dim3(256), 0, stream>>>(pos, pos1, 1024, rsq1, nidx1, ncnt1);
    ballq_kernel<1024, 256><<<dim3(8 * 256), dim3(256), 0, stream>>>(pos1, pos2, 256, rsq2, nidx2, ncnt2);
    ballq_kernel<256, 256><<<dim3(8 * 64), dim3(256), 0, stream>>>(pos2, pos3, 64, rsq3, nidx3, ncnt3);

    sa_conv_kernel<0, 64, 64, 128, 4096><<<dim3(8 * 1024), dim3(256), 0, stream>>>(
        nullptr, pos, pos1, nidx1, ncnt1, sa1_w0, sa1_b0, sa1_w1, sa1_b1, sa1_w2, sa1_b2, x1, 1024);
    sa_conv_kernel<128, 128, 128, 256, 1024><<<dim3(8 * 256), dim3(256), 0, stream>>>(
        x1, pos1, pos2, nidx2, ncnt2, sa2_w0, sa2_b0, sa2_w1, sa2_b1, sa2_w2, sa2_b2, x2, 256);
    sa_conv_kernel<256, 256, 256, 512, 256><<<dim3(8 * 64), dim3(256), 0, stream>>>(
        x2, pos2, pos3, nidx3, ncnt3, sa3_w0, sa3_b0, sa3_w1, sa3_b1, sa3_w2, sa3_b2, x3, 64);

    gsa1_kernel<<<dim3(64), dim3(256), 0, stream>>>(x3, pos3, sa4_w0, sa4_b0, h1g);
    gsa2_kernel<<<dim3(128), dim3(256), 0, stream>>>(h1g, sa4_w1, sa4_b1, out);
}

// Round 2
// 2494.861 us; speedup vs baseline: 1.8560x; 1.8560x over previous
//
#include <hip/hip_runtime.h>

#define DEV __device__ __forceinline__

// ---------- exact (non-contracted) squared distance: matches jnp sum(((a-b)**2), -1) ----------
DEV float d2_exact(float ax, float ay, float az, float bx, float by, float bz) {
    float dx = __fadd_rn(ax, -bx);
    float dy = __fadd_rn(ay, -by);
    float dz = __fadd_rn(az, -bz);
    return __fadd_rn(__fadd_rn(__fmul_rn(dx, dx), __fmul_rn(dy, dy)), __fmul_rn(dz, dz));
}

DEV unsigned long long umax64(unsigned long long a, unsigned long long b) { return a > b ? a : b; }
DEV unsigned long long umin64(unsigned long long a, unsigned long long b) { return a < b ? a : b; }

// =====================================================================================
// FPS: one block per batch. pos [B,N,3] -> pos_out [B,S,3]. Deterministic start idx 0.
// =====================================================================================
template <int N, int S, int T>
__global__ __launch_bounds__(T) void fps_kernel(const float* __restrict__ pos,
                                                float* __restrict__ pos_out) {
    constexpr int C  = N / T;
    constexpr int NW = T / 64;
    __shared__ float sx[N], sy[N], sz[N];
    __shared__ unsigned long long sred[NW];
    __shared__ int scur;
    const int b = blockIdx.x, t = threadIdx.x;
    const float* p = pos + (size_t)b * N * 3;
    for (int i = t; i < N; i += T) { sx[i] = p[3*i]; sy[i] = p[3*i+1]; sz[i] = p[3*i+2]; }
    __syncthreads();
    float px[C], py[C], pz[C], md[C];
    const int base = t * C;
#pragma unroll
    for (int i = 0; i < C; i++) { px[i]=sx[base+i]; py[i]=sy[base+i]; pz[i]=sz[base+i]; md[i]=1e30f; }
    float cx = sx[0], cy = sy[0], cz = sz[0];
    const int lane = t & 63, wave = t >> 6;
    for (int s = 0; s < S; s++) {
        if (t == 0) {
            float* po = pos_out + ((size_t)b * S + s) * 3;
            po[0] = cx; po[1] = cy; po[2] = cz;
        }
        float bv = -1.0f; int bi = 0;
#pragma unroll
        for (int i = 0; i < C; i++) {
            float d = d2_exact(px[i], py[i], pz[i], cx, cy, cz);
            float m = fminf(md[i], d);
            md[i] = m;
            if (m > bv) { bv = m; bi = base + i; }   // strict > keeps first max in chunk
        }
        unsigned long long key =
            ((unsigned long long)__float_as_uint(bv) << 32) | (unsigned long long)(unsigned int)(~bi);
#pragma unroll
        for (int o = 32; o >= 1; o >>= 1) key = umax64(key, __shfl_xor(key, o, 64));
        if (lane == 0) sred[wave] = key;
        __syncthreads();
        if (wave == 0) {
            unsigned long long v = (lane < NW) ? sred[lane] : 0ULL;
#pragma unroll
            for (int o = 8; o >= 1; o >>= 1) v = umax64(v, __shfl_xor(v, o, 64));
            if (lane == 0) scur = (int)(~(unsigned int)v);
        }
        __syncthreads();
        const int cur = scur;
        cx = sx[cur]; cy = sy[cur]; cz = sz[cur];
    }
}

// =====================================================================================
// Ball query: one block per (b,s). Emits the neighbor SET (order-free when count<=K,
// exact top-K extraction with lowest-index ties when count>K).
// =====================================================================================
template <int NSRC, int T>
__global__ __launch_bounds__(T) void ballq_kernel(const float* __restrict__ pos_src,
                                                  const float* __restrict__ pos_dst,
                                                  const int S, const float rsq,
                                                  int* __restrict__ nidx, int* __restrict__ ncnt) {
    __shared__ float d2s[NSRC];
    __shared__ int scnt, sfill;
    __shared__ unsigned long long sred[T / 64];
    const int bs = blockIdx.x, t = threadIdx.x;
    const int b = bs / S;
    const float* pd = pos_dst + (size_t)bs * 3;
    const float qx = pd[0], qy = pd[1], qz = pd[2];
    const float* ps = pos_src + (size_t)b * NSRC * 3;
    if (t == 0) { scnt = 0; sfill = 0; }
    __syncthreads();
    int lc = 0;
    for (int j = t; j < NSRC; j += T) {
        float d2 = d2_exact(ps[3*j], ps[3*j+1], ps[3*j+2], qx, qy, qz);
        d2s[j] = d2;
        lc += (d2 < rsq) ? 1 : 0;
    }
    if (lc) atomicAdd(&scnt, lc);
    __syncthreads();
    const int c = scnt;
    int* mi = nidx + (size_t)bs * 64;
    if (c <= 64) {
        if (t == 0) ncnt[bs] = c;
        for (int j = t; j < NSRC; j += T) {
            if (d2s[j] < rsq) { int p = atomicAdd(&sfill, 1); mi[p] = j; }
        }
    } else {
        if (t == 0) ncnt[bs] = 64;
        const int lane = t & 63, wave = t >> 6;
        for (int k = 0; k < 64; k++) {
            unsigned long long best = ~0ULL;
            for (int j = t; j < NSRC; j += T) {
                unsigned long long key =
                    ((unsigned long long)__float_as_uint(d2s[j]) << 32) | (unsigned int)j;
                best = umin64(best, key);
            }
#pragma unroll
            for (int o = 32; o >= 1; o >>= 1) best = umin64(best, __shfl_xor(best, o, 64));
            if (lane == 0) sred[wave] = best;
            __syncthreads();
            if (t == 0) {
                unsigned long long v = sred[0];
                for (int w = 1; w < T / 64; w++) v = umin64(v, sred[w]);
                int j = (int)(unsigned int)v;
                mi[k] = j;
                d2s[j] = __uint_as_float(0x7F800000u);  // +inf: exclude from later picks
            }
            __syncthreads();
        }
    }
}

// =====================================================================================
// Per-dst GEMM helpers. Activations transposed in LDS: inT[ci][k], row stride LP=68
// floats. TT threads; thread = (tc = t&15 -> 4 cols, tr = t>>4 -> RPT rows), RPT=1024/TT.
// All trip counts compile-time constant; unrolls bounded to keep VGPR pressure low.
// =====================================================================================
#define LP 68

template <int RPT>
DEV void fma_step(const float* __restrict__ inT, const float (*wt)[64],
                  const int cig, const int ci, const int tr, const int tc,
                  float (&acc)[RPT][4]) {
    const float4 w = *(const float4*)(&wt[ci][4 * tc]);
    const float wv[4] = {w.x, w.y, w.z, w.w};
    if constexpr (RPT == 4) {
        const float4 a = *(const float4*)(inT + (size_t)cig * LP + 4 * tr);
        const float av[4] = {a.x, a.y, a.z, a.w};
#pragma unroll
        for (int i = 0; i < 4; i++)
#pragma unroll
            for (int j = 0; j < 4; j++) acc[i][j] = fmaf(av[i], wv[j], acc[i][j]);
    } else {
        const float2 a = *(const float2*)(inT + (size_t)cig * LP + 2 * tr);
        const float av[2] = {a.x, a.y};
#pragma unroll
        for (int i = 0; i < 2; i++)
#pragma unroll
            for (int j = 0; j < 4; j++) acc[i][j] = fmaf(av[i], wv[j], acc[i][j]);
    }
}

template <int CIN, int COUT, bool RELU, int TT>
DEV void gemm_tile(const float* __restrict__ inT, const float* __restrict__ W,
                   const float* __restrict__ bias, float* __restrict__ outT,
                   float (*wt)[64], const int t) {
    constexpr int RPT  = 1024 / TT;
    constexpr int NCH  = CIN / 32;
    constexpr int TAIL = CIN % 32;
    const int tc = t & 15, tr = t >> 4;
    for (int co0 = 0; co0 < COUT; co0 += 64) {
        float acc[RPT][4] = {};
        for (int ch = 0; ch < NCH; ch++) {
            const int ci0 = ch * 32;
            __syncthreads();
            for (int e = t; e < 2048; e += TT) {
                const int co = e & 63, ci = e >> 6;
                wt[ci][co] = W[(size_t)(ci0 + ci) * COUT + co0 + co];
            }
            __syncthreads();
#pragma unroll 4
            for (int ci = 0; ci < 32; ci++)
                fma_step<RPT>(inT, (const float(*)[64])wt, ci0 + ci, ci, tr, tc, acc);
        }
        if constexpr (TAIL > 0) {
            constexpr int ci0 = NCH * 32;
            __syncthreads();
            for (int e = t; e < TAIL * 64; e += TT) {
                const int co = e & 63, ci = e >> 6;
                wt[ci][co] = W[(size_t)(ci0 + ci) * COUT + co0 + co];
            }
            __syncthreads();
#pragma unroll
            for (int ci = 0; ci < TAIL; ci++)
                fma_step<RPT>(inT, (const float(*)[64])wt, ci0 + ci, ci, tr, tc, acc);
        }
#pragma unroll
        for (int j = 0; j < 4; j++) {
            const float bj = bias[co0 + 4 * tc + j];
            if constexpr (RPT == 4) {
                float4 o;
                o.x = acc[0][j] + bj; o.y = acc[1][j] + bj;
                o.z = acc[2][j] + bj; o.w = acc[3][j] + bj;
                if (RELU) {
                    o.x = fmaxf(o.x, 0.f); o.y = fmaxf(o.y, 0.f);
                    o.z = fmaxf(o.z, 0.f); o.w = fmaxf(o.w, 0.f);
                }
                *(float4*)(outT + (size_t)(co0 + 4 * tc + j) * LP + 4 * tr) = o;
            } else {
                float2 o;
                o.x = acc[0][j] + bj; o.y = acc[1][j] + bj;
                if (RELU) { o.x = fmaxf(o.x, 0.f); o.y = fmaxf(o.y, 0.f); }
                *(float2*)(outT + (size_t)(co0 + 4 * tc + j) * LP + 2 * tr) = o;
            }
        }
    }
}

template <int CIN, int COUT, int TT>
DEV void gemm_maxout(const float* __restrict__ inT, const float* __restrict__ W,
                     const float* __restrict__ bias, float* __restrict__ outg,
                     float (*wt)[64], float (*colred)[64], const int t, const int c) {
    constexpr int RPT = 1024 / TT;
    constexpr int NW  = TT / 64;
    constexpr int NCH = CIN / 32;   // CIN here is always a multiple of 32
    const int tc = t & 15, tr = t >> 4, wave = t >> 6;
    for (int co0 = 0; co0 < COUT; co0 += 64) {
        float acc[RPT][4] = {};
        for (int ch = 0; ch < NCH; ch++) {
            const int ci0 = ch * 32;
            __syncthreads();
            for (int e = t; e < 2048; e += TT) {
                const int co = e & 63, ci = e >> 6;
                wt[ci][co] = W[(size_t)(ci0 + ci) * COUT + co0 + co];
            }
            __syncthreads();
#pragma unroll 4
            for (int ci = 0; ci < 32; ci++)
                fma_step<RPT>(inT, (const float(*)[64])wt, ci0 + ci, ci, tr, tc, acc);
        }
        float vr[4];
#pragma unroll
        for (int j = 0; j < 4; j++) {
            const float bj = bias[co0 + 4 * tc + j];
            float m = -1e30f;  // same sentinel as reference mask
#pragma unroll
            for (int i = 0; i < RPT; i++) {
                const float v = acc[i][j] + bj;
                if (RPT * tr + i < c) m = fmaxf(m, v);
            }
            m = fmaxf(m, __shfl_xor(m, 16, 64));
            m = fmaxf(m, __shfl_xor(m, 32, 64));
            vr[j] = m;
        }
        if ((t & 48) == 0) {
#pragma unroll
            for (int j = 0; j < 4; j++) colred[wave][4 * tc + j] = vr[j];
        }
        __syncthreads();
        if (t < 64) {
            float m = colred[0][t];
#pragma unroll
            for (int w = 1; w < NW; w++) m = fmaxf(m, colred[w][t]);
            outg[co0 + t] = m;
        }
        __syncthreads();
    }
}

// =====================================================================================
// SA conv: one block per dst point. Gathers (x_j, rel) into LDS (rows>=count zeroed),
// 3-layer MLP, masked max over neighbors -> x_out[bs].
// =====================================================================================
template <int CX, int C0, int C1, int C2, int NSRC, int TT>
__global__ __launch_bounds__(TT) void sa_conv_kernel(
    const float* __restrict__ x_src, const float* __restrict__ pos_src,
    const float* __restrict__ pos_dst, const int* __restrict__ nidx,
    const int* __restrict__ ncnt,
    const float* __restrict__ w0, const float* __restrict__ b0,
    const float* __restrict__ w1, const float* __restrict__ b1,
    const float* __restrict__ w2, const float* __restrict__ b2,
    float* __restrict__ x_out, const int S) {
    constexpr int CIN = CX + 3;
    constexpr int AR  = (CIN > C1) ? CIN : C1;
    __shared__ float bufA[AR * LP];
    __shared__ float bufB[C0 * LP];
    __shared__ float wt[32][64];
    __shared__ float colred[TT / 64][64];
    const int bs = blockIdx.x, t = threadIdx.x;
    const int b = bs / S;
    const int c = ncnt[bs];
    const int* ni = nidx + (size_t)bs * 64;
    const float* pd = pos_dst + (size_t)bs * 3;
    const float qx = pd[0], qy = pd[1], qz = pd[2];
    if constexpr (CX > 0) {
        constexpr int LG = (CX == 256) ? 8 : 7;
#pragma unroll 4
        for (int e = t; e < 64 * CX; e += TT) {
            const int ci = e & (CX - 1), k = e >> LG;
            float v = 0.f;
            if (k < c) v = x_src[((size_t)b * NSRC + ni[k]) * CX + ci];
            bufA[(size_t)ci * LP + k] = v;
        }
    }
    for (int e = t; e < 192; e += TT) {
        const int k = e & 63, ci = e >> 6;
        float v = 0.f;
        if (k < c) {
            const float* pj = pos_src + ((size_t)b * NSRC + ni[k]) * 3;
            v = (ci == 0 ? pj[0] - qx : (ci == 1 ? pj[1] - qy : pj[2] - qz));
        }
        bufA[(size_t)(CX + ci) * LP + k] = v;
    }
    __syncthreads();
    gemm_tile<CIN, C0, true, TT>(bufA, w0, b0, bufB, wt, t);
    __syncthreads();
    gemm_tile<C0, C1, true, TT>(bufB, w1, b1, bufA, wt, t);
    __syncthreads();
    gemm_maxout<C1, C2, TT>(bufA, w2, b2, x_out + (size_t)bs * C2, wt, colred, t, c);
}

// =====================================================================================
// Global SA: layer 1 (515 -> 512, relu) to ws, layer 2 (512 -> 1024) + max over 64 pts.
// =====================================================================================
__global__ __launch_bounds__(256) void gsa1_kernel(const float* __restrict__ x3,
                                                   const float* __restrict__ pos3,
                                                   const float* __restrict__ w0,
                                                   const float* __restrict__ b0,
                                                   float* __restrict__ h1) {
    __shared__ float at[32][LP];
    __shared__ float wt[32][64];
    const int b = blockIdx.x >> 3, co0 = (blockIdx.x & 7) * 64;
    const int t = threadIdx.x, tc = t & 15, tr = t >> 4;
    float acc[4][4] = {};
    for (int ci0 = 0; ci0 < 515; ci0 += 32) {
        const int cc = (515 - ci0) < 32 ? (515 - ci0) : 32;
        __syncthreads();
        for (int e = t; e < cc * 64; e += 256) {
            const int k = e & 63, ci = e >> 6, cig = ci0 + ci;
            at[ci][k] = (cig < 512) ? x3[((size_t)b * 64 + k) * 512 + cig]
                                    : pos3[((size_t)b * 64 + k) * 3 + (cig - 512)];
        }
        for (int e = t; e < cc * 64; e += 256) {
            const int co = e & 63, ci = e >> 6;
            wt[ci][co] = w0[(size_t)(ci0 + ci) * 512 + co0 + co];
        }
        __syncthreads();
#pragma unroll 4
        for (int ci = 0; ci < 32; ci++) {
            if (ci >= cc) break;
            const float4 a = *(const float4*)&at[ci][4 * tr];
            const float4 w = *(const float4*)&wt[ci][4 * tc];
            const float av[4] = {a.x, a.y, a.z, a.w};
            const float wv[4] = {w.x, w.y, w.z, w.w};
#pragma unroll
            for (int i = 0; i < 4; i++)
#pragma unroll
                for (int j = 0; j < 4; j++) acc[i][j] = fmaf(av[i], wv[j], acc[i][j]);
        }
    }
#pragma unroll
    for (int j = 0; j < 4; j++) {
        const float bj = b0[co0 + 4 * tc + j];
#pragma unroll
        for (int i = 0; i < 4; i++) {
            float v = acc[i][j] + bj;
            v = fmaxf(v, 0.f);
            h1[((size_t)b * 64 + 4 * tr + i) * 512 + co0 + 4 * tc + j] = v;
        }
    }
}

__global__ __launch_bounds__(256) void gsa2_kernel(const float* __restrict__ h1,
                                                   const float* __restrict__ w1,
                                                   const float* __restrict__ b1,
                                                   float* __restrict__ out) {
    __shared__ float at[32][LP];
    __shared__ float wt[32][64];
    __shared__ float colred[4][64];
    const int b = blockIdx.x >> 4, co0 = (blockIdx.x & 15) * 64;
    const int t = threadIdx.x, tc = t & 15, tr = t >> 4, wave = t >> 6;
    float acc[4][4] = {};
    for (int ci0 = 0; ci0 < 512; ci0 += 32) {
        __syncthreads();
        for (int e = t; e < 32 * 64; e += 256) {
            const int k = e & 63, ci = e >> 6;
            at[ci][k] = h1[((size_t)b * 64 + k) * 512 + ci0 + ci];
        }
        for (int e = t; e < 32 * 64; e += 256) {
            const int co = e & 63, ci = e >> 6;
            wt[ci][co] = w1[(size_t)(ci0 + ci) * 1024 + co0 + co];
        }
        __syncthreads();
#pragma unroll 4
        for (int ci = 0; ci < 32; ci++) {
            const float4 a = *(const float4*)&at[ci][4 * tr];
            const float4 w = *(const float4*)&wt[ci][4 * tc];
            const float av[4] = {a.x, a.y, a.z, a.w};
            const float wv[4] = {w.x, w.y, w.z, w.w};
#pragma unroll
            for (int i = 0; i < 4; i++)
#pragma unroll
                for (int j = 0; j < 4; j++) acc[i][j] = fmaf(av[i], wv[j], acc[i][j]);
        }
    }
    float vr[4];
#pragma unroll
    for (int j = 0; j < 4; j++) {
        const float bj = b1[co0 + 4 * tc + j];
        float m = -1e30f;
#pragma unroll
        for (int i = 0; i < 4; i++) m = fmaxf(m, acc[i][j] + bj);
        m = fmaxf(m, __shfl_xor(m, 16, 64));
        m = fmaxf(m, __shfl_xor(m, 32, 64));
        vr[j] = m;
    }
    if ((t & 48) == 0) {
#pragma unroll
        for (int j = 0; j < 4; j++) colred[wave][4 * tc + j] = vr[j];
    }
    __syncthreads();
    if (t < 64) {
        const float m = fmaxf(fmaxf(colred[0][t], colred[1][t]),
                              fmaxf(colred[2][t], colred[3][t]));
        out[(size_t)b * 1024 + co0 + t] = m;
    }
}

// =====================================================================================
extern "C" void kernel_launch(void* const* d_in, const int* in_sizes, int n_in,
                              void* d_out, int out_size, void* d_ws, size_t ws_size,
                              hipStream_t stream) {
    (void)in_sizes; (void)n_in; (void)out_size; (void)ws_size;
    const float* pos    = (const float*)d_in[0];
    const float* sa1_w0 = (const float*)d_in[1];  const float* sa1_b0 = (const float*)d_in[2];
    const float* sa1_w1 = (const float*)d_in[3];  const float* sa1_b1 = (const float*)d_in[4];
    const float* sa1_w2 = (const float*)d_in[5];  const float* sa1_b2 = (const float*)d_in[6];
    const float* sa2_w0 = (const float*)d_in[7];  const float* sa2_b0 = (const float*)d_in[8];
    const float* sa2_w1 = (const float*)d_in[9];  const float* sa2_b1 = (const float*)d_in[10];
    const float* sa2_w2 = (const float*)d_in[11]; const float* sa2_b2 = (const float*)d_in[12];
    const float* sa3_w0 = (const float*)d_in[13]; const float* sa3_b0 = (const float*)d_in[14];
    const float* sa3_w1 = (const float*)d_in[15]; const float* sa3_b1 = (const float*)d_in[16];
    const float* sa3_w2 = (const float*)d_in[17]; const float* sa3_b2 = (const float*)d_in[18];
    const float* sa4_w0 = (const float*)d_in[19]; const float* sa4_b0 = (const float*)d_in[20];
    const float* sa4_w1 = (const float*)d_in[21]; const float* sa4_b1 = (const float*)d_in[22];
    float* out = (float*)d_out;
    char* ws = (char*)d_ws;

    float* pos1 = (float*)(ws + 0);         // [8,1024,3]
    float* pos2 = (float*)(ws + 98304);     // [8,256,3]
    float* pos3 = (float*)(ws + 122880);    // [8,64,3]
    float* x1   = (float*)(ws + 129024);    // [8,1024,128]
    float* x2   = (float*)(ws + 4323328);   // [8,256,256]
    float* x3   = (float*)(ws + 6420480);   // [8,64,512]
    int* nidx1  = (int*)(ws + 7469056);     // [8*1024,64]
    int* ncnt1  = (int*)(ws + 9566208);     // [8*1024]
    int* nidx2  = (int*)(ws + 9598976);     // [8*256,64]
    int* ncnt2  = (int*)(ws + 10123264);    // [8*256]
    int* nidx3  = (int*)(ws + 10131456);    // [8*64,64]
    int* ncnt3  = (int*)(ws + 10262528);    // [8*64]
    float* h1g  = (float*)(ws + 10264576);  // [8*64,512]

    const float rsq1 = (float)(0.2 * 0.2);
    const float rsq2 = (float)(0.4 * 0.4);
    const float rsq3 = (float)(0.8 * 0.8);

    fps_kernel<4096, 1024, 1024><<<dim3(8), dim3(1024), 0, stream>>>(pos, pos1);
    fps_kernel<1024, 256, 256><<<dim3(8), dim3(256), 0, stream>>>(pos1, pos2);
    fps_kernel<256, 64, 256><<<dim3(8), dim3(256), 0, stream>>>(pos2, pos3);

    ballq_kernel<4096, 256><<<dim3(8 * 1024), dim3(256), 0, stream>>>(pos, pos1, 1024, rsq1, nidx1, ncnt1);
    ballq_kernel<1024, 256><<<dim3(8 * 256), dim3(256), 0, stream>>>(pos1, pos2, 256, rsq2, nidx2, ncnt2);
    ballq_kernel<256, 256><<<dim3(8 * 64), dim3(256), 0, stream>>>(pos2, pos3, 64, rsq3, nidx3, ncnt3);

    sa_conv_kernel<0, 64, 64, 128, 4096, 256><<<dim3(8 * 1024), dim3(256), 0, stream>>>(
        nullptr, pos, pos1, nidx1, ncnt1, sa1_w0, sa1_b0, sa1_w1, sa1_b1, sa1_w2, sa1_b2, x1, 1024);
    sa_conv_kernel<128, 128, 128, 256, 1024, 256><<<dim3(8 * 256), dim3(256), 0, stream>>>(
        x1, pos1, pos2, nidx2, ncnt2, sa2_w0, sa2_b0, sa2_w1, sa2_b1, sa2_w2, sa2_b2, x2, 256);
    sa_conv_kernel<256, 256, 256, 512, 256, 512><<<dim3(8 * 64), dim3(512), 0, stream>>>(
        x2, pos2, pos3, nidx3, ncnt3, sa3_w0, sa3_b0, sa3_w1, sa3_b1, sa3_w2, sa3_b2, x3, 64);

    gsa1_kernel<<<dim3(64), dim3(256), 0, stream>>>(x3, pos3, sa4_w0, sa4_b0, h1g);
    gsa2_kernel<<<dim3(128), dim3(256), 0, stream>>>(h1g, sa4_w1, sa4_b1, out);
}

// Round 3
// 2294.940 us; speedup vs baseline: 2.0176x; 1.0871x over previous
//
#include <hip/hip_runtime.h>

#define DEV __device__ __forceinline__

// ---------- exact (non-contracted) squared distance: matches jnp sum(((a-b)**2), -1) ----------
DEV float d2_exact(float ax, float ay, float az, float bx, float by, float bz) {
    float dx = __fadd_rn(ax, -bx);
    float dy = __fadd_rn(ay, -by);
    float dz = __fadd_rn(az, -bz);
    return __fadd_rn(__fadd_rn(__fmul_rn(dx, dx), __fmul_rn(dy, dy)), __fmul_rn(dz, dz));
}

DEV unsigned long long umax64(unsigned long long a, unsigned long long b) { return a > b ? a : b; }
DEV unsigned long long umin64(unsigned long long a, unsigned long long b) { return a < b ? a : b; }

// =====================================================================================
// FPS: one block per batch. pos [B,N,3] -> pos_out [B,S,3]. Deterministic start idx 0.
// Reduction: per-thread strict-> argmax over its CONTIGUOUS chunk (lowest idx on tie),
// f32 max butterfly in-wave, ballot+ffs picks lowest lane (=lowest idx), packed-u64
// cross-wave level. Matches jnp.argmax (lowest linear index among global max).
// =====================================================================================
template <int N, int S, int T>
__global__ __launch_bounds__(T) void fps_kernel(const float* __restrict__ pos,
                                                float* __restrict__ pos_out) {
    constexpr int C  = N / T;
    constexpr int NW = T / 64;
    __shared__ float sx[N], sy[N], sz[N];
    __shared__ unsigned long long sred[NW];
    __shared__ int scur;
    const int b = blockIdx.x, t = threadIdx.x;
    const float* p = pos + (size_t)b * N * 3;
    for (int i = t; i < N; i += T) { sx[i] = p[3*i]; sy[i] = p[3*i+1]; sz[i] = p[3*i+2]; }
    __syncthreads();
    float px[C], py[C], pz[C], md[C];
    const int base = t * C;
#pragma unroll
    for (int i = 0; i < C; i++) { px[i]=sx[base+i]; py[i]=sy[base+i]; pz[i]=sz[base+i]; md[i]=1e30f; }
    float cx = sx[0], cy = sy[0], cz = sz[0];
    const int lane = t & 63, wave = t >> 6;
    for (int s = 0; s < S; s++) {
        if (t == 0) {
            float* po = pos_out + ((size_t)b * S + s) * 3;
            po[0] = cx; po[1] = cy; po[2] = cz;
        }
        float bv = -1.0f; int bi = 0;
#pragma unroll
        for (int i = 0; i < C; i++) {
            float d = d2_exact(px[i], py[i], pz[i], cx, cy, cz);
            float m = fminf(md[i], d);
            md[i] = m;
            if (m > bv) { bv = m; bi = base + i; }   // strict > keeps first max in chunk
        }
        // in-wave: value-only butterfly (f32 >= 0 here), then lowest lane holding the max
        float wm = bv;
#pragma unroll
        for (int o = 32; o >= 1; o >>= 1) wm = fmaxf(wm, __shfl_xor(wm, o, 64));
        unsigned long long eq = __ballot(bv == wm);
        const int srcl = __ffsll(eq) - 1;
        const int wbi  = __shfl(bi, srcl, 64);
        if (lane == 0)
            sred[wave] = ((unsigned long long)__float_as_uint(wm) << 32) |
                         (unsigned long long)(unsigned int)(~wbi);
        __syncthreads();
        if (wave == 0) {
            unsigned long long v = (lane < NW) ? sred[lane] : 0ULL;
#pragma unroll
            for (int o = NW > 4 ? 8 : 4; o >= 1; o >>= 1) v = umax64(v, __shfl_xor(v, o, 64));
            if (lane == 0) scur = (int)(~(unsigned int)v);
        }
        __syncthreads();
        const int cur = scur;
        cx = sx[cur]; cy = sy[cur]; cz = sz[cur];
    }
}

// =====================================================================================
// Ball query: one block per (b,s). Emits the neighbor SET (order-free when count<=K,
// exact top-K extraction with lowest-index ties when count>K).
// =====================================================================================
template <int NSRC, int T>
__global__ __launch_bounds__(T) void ballq_kernel(const float* __restrict__ pos_src,
                                                  const float* __restrict__ pos_dst,
                                                  const int S, const float rsq,
                                                  int* __restrict__ nidx, int* __restrict__ ncnt) {
    __shared__ float d2s[NSRC];
    __shared__ int scnt, sfill;
    __shared__ unsigned long long sred[T / 64];
    const int bs = blockIdx.x, t = threadIdx.x;
    const int b = bs / S;
    const float* pd = pos_dst + (size_t)bs * 3;
    const float qx = pd[0], qy = pd[1], qz = pd[2];
    const float* ps = pos_src + (size_t)b * NSRC * 3;
    if (t == 0) { scnt = 0; sfill = 0; }
    __syncthreads();
    int lc = 0;
    for (int j = t; j < NSRC; j += T) {
        float d2 = d2_exact(ps[3*j], ps[3*j+1], ps[3*j+2], qx, qy, qz);
        d2s[j] = d2;
        lc += (d2 < rsq) ? 1 : 0;
    }
    if (lc) atomicAdd(&scnt, lc);
    __syncthreads();
    const int c = scnt;
    int* mi = nidx + (size_t)bs * 64;
    if (c <= 64) {
        if (t == 0) ncnt[bs] = c;
        for (int j = t; j < NSRC; j += T) {
            if (d2s[j] < rsq) { int p = atomicAdd(&sfill, 1); mi[p] = j; }
        }
    } else {
        if (t == 0) ncnt[bs] = 64;
        const int lane = t & 63, wave = t >> 6;
        for (int k = 0; k < 64; k++) {
            unsigned long long best = ~0ULL;
            for (int j = t; j < NSRC; j += T) {
                unsigned long long key =
                    ((unsigned long long)__float_as_uint(d2s[j]) << 32) | (unsigned int)j;
                best = umin64(best, key);
            }
#pragma unroll
            for (int o = 32; o >= 1; o >>= 1) best = umin64(best, __shfl_xor(best, o, 64));
            if (lane == 0) sred[wave] = best;
            __syncthreads();
            if (t == 0) {
                unsigned long long v = sred[0];
                for (int w = 1; w < T / 64; w++) v = umin64(v, sred[w]);
                int j = (int)(unsigned int)v;
                mi[k] = j;
                d2s[j] = __uint_as_float(0x7F800000u);  // +inf: exclude from later picks
            }
            __syncthreads();
        }
    }
}

// =====================================================================================
// Per-dst GEMM helpers. Activations transposed in LDS: inT[ci][k], row stride LP=68
// floats. TT threads; thread = (tc = t&15 -> 4 cols, tr = t>>4 -> RPT rows), RPT=1024/TT.
// All trip counts compile-time constant; unrolls bounded to keep VGPR pressure low.
// =====================================================================================
#define LP 68

template <int RPT>
DEV void fma_step(const float* __restrict__ inT, const float (*wt)[64],
                  const int cig, const int ci, const int tr, const int tc,
                  float (&acc)[RPT][4]) {
    const float4 w = *(const float4*)(&wt[ci][4 * tc]);
    const float wv[4] = {w.x, w.y, w.z, w.w};
    if constexpr (RPT == 4) {
        const float4 a = *(const float4*)(inT + (size_t)cig * LP + 4 * tr);
        const float av[4] = {a.x, a.y, a.z, a.w};
#pragma unroll
        for (int i = 0; i < 4; i++)
#pragma unroll
            for (int j = 0; j < 4; j++) acc[i][j] = fmaf(av[i], wv[j], acc[i][j]);
    } else {
        const float2 a = *(const float2*)(inT + (size_t)cig * LP + 2 * tr);
        const float av[2] = {a.x, a.y};
#pragma unroll
        for (int i = 0; i < 2; i++)
#pragma unroll
            for (int j = 0; j < 4; j++) acc[i][j] = fmaf(av[i], wv[j], acc[i][j]);
    }
}

template <int CIN, int COUT, bool RELU, int TT>
DEV void gemm_tile(const float* __restrict__ inT, const float* __restrict__ W,
                   const float* __restrict__ bias, float* __restrict__ outT,
                   float (*wt)[64], const int t) {
    constexpr int RPT  = 1024 / TT;
    constexpr int NCH  = CIN / 32;
    constexpr int TAIL = CIN % 32;
    const int tc = t & 15, tr = t >> 4;
    for (int co0 = 0; co0 < COUT; co0 += 64) {
        float acc[RPT][4] = {};
        for (int ch = 0; ch < NCH; ch++) {
            const int ci0 = ch * 32;
            __syncthreads();
            for (int e = t; e < 2048; e += TT) {
                const int co = e & 63, ci = e >> 6;
                wt[ci][co] = W[(size_t)(ci0 + ci) * COUT + co0 + co];
            }
            __syncthreads();
#pragma unroll 4
            for (int ci = 0; ci < 32; ci++)
                fma_step<RPT>(inT, (const float(*)[64])wt, ci0 + ci, ci, tr, tc, acc);
        }
        if constexpr (TAIL > 0) {
            constexpr int ci0 = NCH * 32;
            __syncthreads();
            for (int e = t; e < TAIL * 64; e += TT) {
                const int co = e & 63, ci = e >> 6;
                wt[ci][co] = W[(size_t)(ci0 + ci) * COUT + co0 + co];
            }
            __syncthreads();
#pragma unroll
            for (int ci = 0; ci < TAIL; ci++)
                fma_step<RPT>(inT, (const float(*)[64])wt, ci0 + ci, ci, tr, tc, acc);
        }
#pragma unroll
        for (int j = 0; j < 4; j++) {
            const float bj = bias[co0 + 4 * tc + j];
            if constexpr (RPT == 4) {
                float4 o;
                o.x = acc[0][j] + bj; o.y = acc[1][j] + bj;
                o.z = acc[2][j] + bj; o.w = acc[3][j] + bj;
                if (RELU) {
                    o.x = fmaxf(o.x, 0.f); o.y = fmaxf(o.y, 0.f);
                    o.z = fmaxf(o.z, 0.f); o.w = fmaxf(o.w, 0.f);
                }
                *(float4*)(outT + (size_t)(co0 + 4 * tc + j) * LP + 4 * tr) = o;
            } else {
                float2 o;
                o.x = acc[0][j] + bj; o.y = acc[1][j] + bj;
                if (RELU) { o.x = fmaxf(o.x, 0.f); o.y = fmaxf(o.y, 0.f); }
                *(float2*)(outT + (size_t)(co0 + 4 * tc + j) * LP + 2 * tr) = o;
            }
        }
    }
}

template <int CIN, int COUT, int TT>
DEV void gemm_maxout(const float* __restrict__ inT, const float* __restrict__ W,
                     const float* __restrict__ bias, float* __restrict__ outg,
                     float (*wt)[64], float (*colred)[64], const int t, const int c) {
    constexpr int RPT = 1024 / TT;
    constexpr int NW  = TT / 64;
    constexpr int NCH = CIN / 32;   // CIN here is always a multiple of 32
    const int tc = t & 15, tr = t >> 4, wave = t >> 6;
    for (int co0 = 0; co0 < COUT; co0 += 64) {
        float acc[RPT][4] = {};
        for (int ch = 0; ch < NCH; ch++) {
            const int ci0 = ch * 32;
            __syncthreads();
            for (int e = t; e < 2048; e += TT) {
                const int co = e & 63, ci = e >> 6;
                wt[ci][co] = W[(size_t)(ci0 + ci) * COUT + co0 + co];
            }
            __syncthreads();
#pragma unroll 4
            for (int ci = 0; ci < 32; ci++)
                fma_step<RPT>(inT, (const float(*)[64])wt, ci0 + ci, ci, tr, tc, acc);
        }
        float vr[4];
#pragma unroll
        for (int j = 0; j < 4; j++) {
            const float bj = bias[co0 + 4 * tc + j];
            float m = -1e30f;  // same sentinel as reference mask
#pragma unroll
            for (int i = 0; i < RPT; i++) {
                const float v = acc[i][j] + bj;
                if (RPT * tr + i < c) m = fmaxf(m, v);
            }
            m = fmaxf(m, __shfl_xor(m, 16, 64));
            m = fmaxf(m, __shfl_xor(m, 32, 64));
            vr[j] = m;
        }
        if ((t & 48) == 0) {
#pragma unroll
            for (int j = 0; j < 4; j++) colred[wave][4 * tc + j] = vr[j];
        }
        __syncthreads();
        if (t < 64) {
            float m = colred[0][t];
#pragma unroll
            for (int w = 1; w < NW; w++) m = fmaxf(m, colred[w][t]);
            outg[co0 + t] = m;
        }
        __syncthreads();
    }
}

// =====================================================================================
// SA conv: one block per dst point. Gathers (x_j, rel) into LDS (rows>=count zeroed),
// 3-layer MLP, masked max over neighbors -> x_out[bs].
// =====================================================================================
template <int CX, int C0, int C1, int C2, int NSRC, int TT>
__global__ __launch_bounds__(TT) void sa_conv_kernel(
    const float* __restrict__ x_src, const float* __restrict__ pos_src,
    const float* __restrict__ pos_dst, const int* __restrict__ nidx,
    const int* __restrict__ ncnt,
    const float* __restrict__ w0, const float* __restrict__ b0,
    const float* __restrict__ w1, const float* __restrict__ b1,
    const float* __restrict__ w2, const float* __restrict__ b2,
    float* __restrict__ x_out, const int S) {
    constexpr int CIN = CX + 3;
    constexpr int AR  = (CIN > C1) ? CIN : C1;
    __shared__ float bufA[AR * LP];
    __shared__ float bufB[C0 * LP];
    __shared__ float wt[32][64];
    __shared__ float colred[TT / 64][64];
    const int bs = blockIdx.x, t = threadIdx.x;
    const int b = bs / S;
    const int c = ncnt[bs];
    const int* ni = nidx + (size_t)bs * 64;
    const float* pd = pos_dst + (size_t)bs * 3;
    const float qx = pd[0], qy = pd[1], qz = pd[2];
    if constexpr (CX > 0) {
        constexpr int LG = (CX == 256) ? 8 : 7;
#pragma unroll 4
        for (int e = t; e < 64 * CX; e += TT) {
            const int ci = e & (CX - 1), k = e >> LG;
            float v = 0.f;
            if (k < c) v = x_src[((size_t)b * NSRC + ni[k]) * CX + ci];
            bufA[(size_t)ci * LP + k] = v;
        }
    }
    for (int e = t; e < 192; e += TT) {
        const int k = e & 63, ci = e >> 6;
        float v = 0.f;
        if (k < c) {
            const float* pj = pos_src + ((size_t)b * NSRC + ni[k]) * 3;
            v = (ci == 0 ? pj[0] - qx : (ci == 1 ? pj[1] - qy : pj[2] - qz));
        }
        bufA[(size_t)(CX + ci) * LP + k] = v;
    }
    __syncthreads();
    gemm_tile<CIN, C0, true, TT>(bufA, w0, b0, bufB, wt, t);
    __syncthreads();
    gemm_tile<C0, C1, true, TT>(bufB, w1, b1, bufA, wt, t);
    __syncthreads();
    gemm_maxout<C1, C2, TT>(bufA, w2, b2, x_out + (size_t)bs * C2, wt, colred, t, c);
}

// =====================================================================================
// Global SA: layer 1 (515 -> 512, relu) to ws, layer 2 (512 -> 1024) + max over 64 pts.
// =====================================================================================
__global__ __launch_bounds__(256) void gsa1_kernel(const float* __restrict__ x3,
                                                   const float* __restrict__ pos3,
                                                   const float* __restrict__ w0,
                                                   const float* __restrict__ b0,
                                                   float* __restrict__ h1) {
    __shared__ float at[32][LP];
    __shared__ float wt[32][64];
    const int b = blockIdx.x >> 3, co0 = (blockIdx.x & 7) * 64;
    const int t = threadIdx.x, tc = t & 15, tr = t >> 4;
    float acc[4][4] = {};
    for (int ci0 = 0; ci0 < 515; ci0 += 32) {
        const int cc = (515 - ci0) < 32 ? (515 - ci0) : 32;
        __syncthreads();
        for (int e = t; e < cc * 64; e += 256) {
            const int k = e & 63, ci = e >> 6, cig = ci0 + ci;
            at[ci][k] = (cig < 512) ? x3[((size_t)b * 64 + k) * 512 + cig]
                                    : pos3[((size_t)b * 64 + k) * 3 + (cig - 512)];
        }
        for (int e = t; e < cc * 64; e += 256) {
            const int co = e & 63, ci = e >> 6;
            wt[ci][co] = w0[(size_t)(ci0 + ci) * 512 + co0 + co];
        }
        __syncthreads();
#pragma unroll 4
        for (int ci = 0; ci < 32; ci++) {
            if (ci >= cc) break;
            const float4 a = *(const float4*)&at[ci][4 * tr];
            const float4 w = *(const float4*)&wt[ci][4 * tc];
            const float av[4] = {a.x, a.y, a.z, a.w};
            const float wv[4] = {w.x, w.y, w.z, w.w};
#pragma unroll
            for (int i = 0; i < 4; i++)
#pragma unroll
                for (int j = 0; j < 4; j++) acc[i][j] = fmaf(av[i], wv[j], acc[i][j]);
        }
    }
#pragma unroll
    for (int j = 0; j < 4; j++) {
        const float bj = b0[co0 + 4 * tc + j];
#pragma unroll
        for (int i = 0; i < 4; i++) {
            float v = acc[i][j] + bj;
            v = fmaxf(v, 0.f);
            h1[((size_t)b * 64 + 4 * tr + i) * 512 + co0 + 4 * tc + j] = v;
        }
    }
}

__global__ __launch_bounds__(256) void gsa2_kernel(const float* __restrict__ h1,
                                                   const float* __restrict__ w1,
                                                   const float* __restrict__ b1,
                                                   float* __restrict__ out) {
    __shared__ float at[32][LP];
    __shared__ float wt[32][64];
    __shared__ float colred[4][64];
    const int b = blockIdx.x >> 4, co0 = (blockIdx.x & 15) * 64;
    const int t = threadIdx.x, tc = t & 15, tr = t >> 4, wave = t >> 6;
    float acc[4][4] = {};
    for (int ci0 = 0; ci0 < 512; ci0 += 32) {
        __syncthreads();
        for (int e = t; e < 32 * 64; e += 256) {
            const int k = e & 63, ci = e >> 6;
            at[ci][k] = h1[((size_t)b * 64 + k) * 512 + ci0 + ci];
        }
        for (int e = t; e < 32 * 64; e += 256) {
            const int co = e & 63, ci = e >> 6;
            wt[ci][co] = w1[(size_t)(ci0 + ci) * 1024 + co0 + co];
        }
        __syncthreads();
#pragma unroll 4
        for (int ci = 0; ci < 32; ci++) {
            const float4 a = *(const float4*)&at[ci][4 * tr];
            const float4 w = *(const float4*)&wt[ci][4 * tc];
            const float av[4] = {a.x, a.y, a.z, a.w};
            const float wv[4] = {w.x, w.y, w.z, w.w};
#pragma unroll
            for (int i = 0; i < 4; i++)
#pragma unroll
                for (int j = 0; j < 4; j++) acc[i][j] = fmaf(av[i], wv[j], acc[i][j]);
        }
    }
    float vr[4];
#pragma unroll
    for (int j = 0; j < 4; j++) {
        const float bj = b1[co0 + 4 * tc + j];
        float m = -1e30f;
#pragma unroll
        for (int i = 0; i < 4; i++) m = fmaxf(m, acc[i][j] + bj);
        m = fmaxf(m, __shfl_xor(m, 16, 64));
        m = fmaxf(m, __shfl_xor(m, 32, 64));
        vr[j] = m;
    }
    if ((t & 48) == 0) {
#pragma unroll
        for (int j = 0; j < 4; j++) colred[wave][4 * tc + j] = vr[j];
    }
    __syncthreads();
    if (t < 64) {
        const float m = fmaxf(fmaxf(colred[0][t], colred[1][t]),
                              fmaxf(colred[2][t], colred[3][t]));
        out[(size_t)b * 1024 + co0 + t] = m;
    }
}

// =====================================================================================
extern "C" void kernel_launch(void* const* d_in, const int* in_sizes, int n_in,
                              void* d_out, int out_size, void* d_ws, size_t ws_size,
                              hipStream_t stream) {
    (void)in_sizes; (void)n_in; (void)out_size; (void)ws_size;
    const float* pos    = (const float*)d_in[0];
    const float* sa1_w0 = (const float*)d_in[1];  const float* sa1_b0 = (const float*)d_in[2];
    const float* sa1_w1 = (const float*)d_in[3];  const float* sa1_b1 = (const float*)d_in[4];
    const float* sa1_w2 = (const float*)d_in[5];  const float* sa1_b2 = (const float*)d_in[6];
    const float* sa2_w0 = (const float*)d_in[7];  const float* sa2_b0 = (const float*)d_in[8];
    const float* sa2_w1 = (const float*)d_in[9];  const float* sa2_b1 = (const float*)d_in[10];
    const float* sa2_w2 = (const float*)d_in[11]; const float* sa2_b2 = (const float*)d_in[12];
    const float* sa3_w0 = (const float*)d_in[13]; const float* sa3_b0 = (const float*)d_in[14];
    const float* sa3_w1 = (const float*)d_in[15]; const float* sa3_b1 = (const float*)d_in[16];
    const float* sa3_w2 = (const float*)d_in[17]; const float* sa3_b2 = (const float*)d_in[18];
    const float* sa4_w0 = (const float*)d_in[19]; const float* sa4_b0 = (const float*)d_in[20];
    const float* sa4_w1 = (const float*)d_in[21]; const float* sa4_b1 = (const float*)d_in[22];
    float* out = (float*)d_out;
    char* ws = (char*)d_ws;

    float* pos1 = (float*)(ws + 0);         // [8,1024,3]
    float* pos2 = (float*)(ws + 98304);     // [8,256,3]
    float* pos3 = (float*)(ws + 122880);    // [8,64,3]
    float* x1   = (float*)(ws + 129024);    // [8,1024,128]
    float* x2   = (float*)(ws + 4323328);   // [8,256,256]
    float* x3   = (float*)(ws + 6420480);   // [8,64,512]
    int* nidx1  = (int*)(ws + 7469056);     // [8*1024,64]
    int* ncnt1  = (int*)(ws + 9566208);     // [8*1024]
    int* nidx2  = (int*)(ws + 9598976);     // [8*256,64]
    int* ncnt2  = (int*)(ws + 10123264);    // [8*256]
    int* nidx3  = (int*)(ws + 10131456);    // [8*64,64]
    int* ncnt3  = (int*)(ws + 10262528);    // [8*64]
    float* h1g  = (float*)(ws + 10264576);  // [8*64,512]

    const float rsq1 = (float)(0.2 * 0.2);
    const float rsq2 = (float)(0.4 * 0.4);
    const float rsq3 = (float)(0.8 * 0.8);

    fps_kernel<4096, 1024, 256><<<dim3(8), dim3(256), 0, stream>>>(pos, pos1);
    fps_kernel<1024, 256, 256><<<dim3(8), dim3(256), 0, stream>>>(pos1, pos2);
    fps_kernel<256, 64, 256><<<dim3(8), dim3(256), 0, stream>>>(pos2, pos3);

    ballq_kernel<4096, 256><<<dim3(8 * 1024), dim3(256), 0, stream>>>(pos, pos1, 1024, rsq1, nidx1, ncnt1);
    ballq_kernel<1024, 256><<<dim3(8 * 256), dim3(256), 0, stream>>>(pos1, pos2, 256, rsq2, nidx2, ncnt2);
    ballq_kernel<256, 256><<<dim3(8 * 64), dim3(256), 0, stream>>>(pos2, pos3, 64, rsq3, nidx3, ncnt3);

    sa_conv_kernel<0, 64, 64, 128, 4096, 256><<<dim3(8 * 1024), dim3(256), 0, stream>>>(
        nullptr, pos, pos1, nidx1, ncnt1, sa1_w0, sa1_b0, sa1_w1, sa1_b1, sa1_w2, sa1_b2, x1, 1024);
    sa_conv_kernel<128, 128, 128, 256, 1024, 256><<<dim3(8 * 256), dim3(256), 0, stream>>>(
        x1, pos1, pos2, nidx2, ncnt2, sa2_w0, sa2_b0, sa2_w1, sa2_b1, sa2_w2, sa2_b2, x2, 256);
    sa_conv_kernel<256, 256, 256, 512, 256, 512><<<dim3(8 * 64), dim3(512), 0, stream>>>(
        x2, pos2, pos3, nidx3, ncnt3, sa3_w0, sa3_b0, sa3_w1, sa3_b1, sa3_w2, sa3_b2, x3, 64);

    gsa1_kernel<<<dim3(64), dim3(256), 0, stream>>>(x3, pos3, sa4_w0, sa4_b0, h1g);
    gsa2_kernel<<<dim3(128), dim3(256), 0, stream>>>(h1g, sa4_w1, sa4_b1, out);
}

// Round 4
// 1916.411 us; speedup vs baseline: 2.4162x; 1.1975x over previous
//
#include <hip/hip_runtime.h>

#define DEV __device__ __forceinline__

// ---------- exact (non-contracted) squared distance: matches jnp sum(((a-b)**2), -1) ----------
DEV float d2_exact(float ax, float ay, float az, float bx, float by, float bz) {
    float dx = __fadd_rn(ax, -bx);
    float dy = __fadd_rn(ay, -by);
    float dz = __fadd_rn(az, -bz);
    return __fadd_rn(__fadd_rn(__fmul_rn(dx, dx), __fmul_rn(dy, dy)), __fmul_rn(dz, dz));
}

DEV unsigned long long umax64(unsigned long long a, unsigned long long b) { return a > b ? a : b; }
DEV unsigned long long umin64(unsigned long long a, unsigned long long b) { return a < b ? a : b; }

// ---------- DPP wave64 max (VALU-only, no LDS): result broadcast via readlane ----------
template <int CTRL>
DEV float dpp_fmax(float x) {
    const int xi = __float_as_int(x);
    const int yi = __builtin_amdgcn_update_dpp(xi, xi, CTRL, 0xF, 0xF, false);
    return fmaxf(x, __int_as_float(yi));
}

DEV float wave_fmax_bcast(float x) {
    x = dpp_fmax<0x111>(x);  // row_shr:1
    x = dpp_fmax<0x112>(x);  // row_shr:2
    x = dpp_fmax<0x114>(x);  // row_shr:4
    x = dpp_fmax<0x118>(x);  // row_shr:8
    x = dpp_fmax<0x142>(x);  // row_bcast:15
    x = dpp_fmax<0x143>(x);  // row_bcast:31  -> lane63 holds wave max
    return __int_as_float(__builtin_amdgcn_readlane(__float_as_int(x), 63));
}

// =====================================================================================
// FPS: one block per batch. pos [B,N,3] -> pos_out [B,S,3]. Deterministic start idx 0.
// Per-iter: per-thread argmax over contiguous chunk (strict > = lowest idx on tie),
// DPP value-max + ballot/ffs/readlane for the index (all VALU/SALU), ONE barrier,
// all waves redundantly reduce the NW packed keys. Matches jnp.argmax tie-break.
// =====================================================================================
template <int N, int S, int T>
__global__ __launch_bounds__(T) void fps_kernel(const float* __restrict__ pos,
                                                float* __restrict__ pos_out) {
    constexpr int C  = N / T;
    constexpr int NW = T / 64;
    __shared__ float sx[N], sy[N], sz[N];
    __shared__ unsigned long long sred[2][NW];
    const int b = blockIdx.x, t = threadIdx.x;
    const float* p = pos + (size_t)b * N * 3;
    for (int i = t; i < N; i += T) { sx[i] = p[3*i]; sy[i] = p[3*i+1]; sz[i] = p[3*i+2]; }
    __syncthreads();
    float px[C], py[C], pz[C], md[C];
    const int base = t * C;
#pragma unroll
    for (int i = 0; i < C; i++) { px[i]=sx[base+i]; py[i]=sy[base+i]; pz[i]=sz[base+i]; md[i]=1e30f; }
    float cx = sx[0], cy = sy[0], cz = sz[0];
    const int lane = t & 63, wave = t >> 6;
    for (int s = 0; s < S; s++) {
        if (t == 0) {
            float* po = pos_out + ((size_t)b * S + s) * 3;
            po[0] = cx; po[1] = cy; po[2] = cz;
        }
        float bv = -1.0f; int bi = 0;
#pragma unroll
        for (int i = 0; i < C; i++) {
            float d = d2_exact(px[i], py[i], pz[i], cx, cy, cz);
            float m = fminf(md[i], d);
            md[i] = m;
            if (m > bv) { bv = m; bi = base + i; }   // strict > keeps first max in chunk
        }
        const float wm = wave_fmax_bcast(bv);             // wave max, broadcast (SGPR)
        const unsigned long long eq = __ballot(bv == wm); // lanes holding the max
        const int srcl = __ffsll(eq) - 1;                 // lowest lane = lowest index
        const int wbi  = __builtin_amdgcn_readlane(bi, srcl);
        if (lane == 0)
            sred[s & 1][wave] = ((unsigned long long)__float_as_uint(wm) << 32) |
                                (unsigned long long)(unsigned int)(~wbi);
        __syncthreads();
        unsigned long long v = sred[s & 1][0];
#pragma unroll
        for (int w = 1; w < NW; w++) v = umax64(v, sred[s & 1][w]);
        const int cur = (int)(~(unsigned int)v);
        cx = sx[cur]; cy = sy[cur]; cz = sz[cur];
    }
}

// =====================================================================================
// Ball query: one block per (b,s). Emits the neighbor SET (order-free when count<=K,
// exact top-K extraction with lowest-index ties when count>K).
// =====================================================================================
template <int NSRC, int T>
__global__ __launch_bounds__(T) void ballq_kernel(const float* __restrict__ pos_src,
                                                  const float* __restrict__ pos_dst,
                                                  const int S, const float rsq,
                                                  int* __restrict__ nidx, int* __restrict__ ncnt) {
    __shared__ float d2s[NSRC];
    __shared__ int scnt, sfill;
    __shared__ unsigned long long sred[T / 64];
    const int bs = blockIdx.x, t = threadIdx.x;
    const int b = bs / S;
    const float* pd = pos_dst + (size_t)bs * 3;
    const float qx = pd[0], qy = pd[1], qz = pd[2];
    const float* ps = pos_src + (size_t)b * NSRC * 3;
    if (t == 0) { scnt = 0; sfill = 0; }
    __syncthreads();
    int lc = 0;
    for (int j = t; j < NSRC; j += T) {
        float d2 = d2_exact(ps[3*j], ps[3*j+1], ps[3*j+2], qx, qy, qz);
        d2s[j] = d2;
        lc += (d2 < rsq) ? 1 : 0;
    }
    if (lc) atomicAdd(&scnt, lc);
    __syncthreads();
    const int c = scnt;
    int* mi = nidx + (size_t)bs * 64;
    if (c <= 64) {
        if (t == 0) ncnt[bs] = c;
        for (int j = t; j < NSRC; j += T) {
            if (d2s[j] < rsq) { int p = atomicAdd(&sfill, 1); mi[p] = j; }
        }
    } else {
        if (t == 0) ncnt[bs] = 64;
        const int lane = t & 63, wave = t >> 6;
        for (int k = 0; k < 64; k++) {
            unsigned long long best = ~0ULL;
            for (int j = t; j < NSRC; j += T) {
                unsigned long long key =
                    ((unsigned long long)__float_as_uint(d2s[j]) << 32) | (unsigned int)j;
                best = umin64(best, key);
            }
#pragma unroll
            for (int o = 32; o >= 1; o >>= 1) best = umin64(best, __shfl_xor(best, o, 64));
            if (lane == 0) sred[wave] = best;
            __syncthreads();
            if (t == 0) {
                unsigned long long v = sred[0];
                for (int w = 1; w < T / 64; w++) v = umin64(v, sred[w]);
                int j = (int)(unsigned int)v;
                mi[k] = j;
                d2s[j] = __uint_as_float(0x7F800000u);  // +inf: exclude from later picks
            }
            __syncthreads();
        }
    }
}

// =====================================================================================
// Per-dst GEMM helpers. Activations transposed in LDS: inT[ci][k], row stride LP=68
// floats. TT threads; thread = (tc = t&15 -> 4 cols, tr = t>>4 -> RPT rows), RPT=1024/TT.
// All trip counts compile-time constant; unrolls bounded to keep VGPR pressure low.
// =====================================================================================
#define LP 68

template <int RPT>
DEV void fma_step(const float* __restrict__ inT, const float (*wt)[64],
                  const int cig, const int ci, const int tr, const int tc,
                  float (&acc)[RPT][4]) {
    const float4 w = *(const float4*)(&wt[ci][4 * tc]);
    const float wv[4] = {w.x, w.y, w.z, w.w};
    if constexpr (RPT == 4) {
        const float4 a = *(const float4*)(inT + (size_t)cig * LP + 4 * tr);
        const float av[4] = {a.x, a.y, a.z, a.w};
#pragma unroll
        for (int i = 0; i < 4; i++)
#pragma unroll
            for (int j = 0; j < 4; j++) acc[i][j] = fmaf(av[i], wv[j], acc[i][j]);
    } else {
        const float2 a = *(const float2*)(inT + (size_t)cig * LP + 2 * tr);
        const float av[2] = {a.x, a.y};
#pragma unroll
        for (int i = 0; i < 2; i++)
#pragma unroll
            for (int j = 0; j < 4; j++) acc[i][j] = fmaf(av[i], wv[j], acc[i][j]);
    }
}

template <int CIN, int COUT, bool RELU, int TT>
DEV void gemm_tile(const float* __restrict__ inT, const float* __restrict__ W,
                   const float* __restrict__ bias, float* __restrict__ outT,
                   float (*wt)[64], const int t) {
    constexpr int RPT  = 1024 / TT;
    constexpr int NCH  = CIN / 32;
    constexpr int TAIL = CIN % 32;
    const int tc = t & 15, tr = t >> 4;
    for (int co0 = 0; co0 < COUT; co0 += 64) {
        float acc[RPT][4] = {};
        for (int ch = 0; ch < NCH; ch++) {
            const int ci0 = ch * 32;
            __syncthreads();
            for (int e = t; e < 2048; e += TT) {
                const int co = e & 63, ci = e >> 6;
                wt[ci][co] = W[(size_t)(ci0 + ci) * COUT + co0 + co];
            }
            __syncthreads();
#pragma unroll 4
            for (int ci = 0; ci < 32; ci++)
                fma_step<RPT>(inT, (const float(*)[64])wt, ci0 + ci, ci, tr, tc, acc);
        }
        if constexpr (TAIL > 0) {
            constexpr int ci0 = NCH * 32;
            __syncthreads();
            for (int e = t; e < TAIL * 64; e += TT) {
                const int co = e & 63, ci = e >> 6;
                wt[ci][co] = W[(size_t)(ci0 + ci) * COUT + co0 + co];
            }
            __syncthreads();
#pragma unroll
            for (int ci = 0; ci < TAIL; ci++)
                fma_step<RPT>(inT, (const float(*)[64])wt, ci0 + ci, ci, tr, tc, acc);
        }
#pragma unroll
        for (int j = 0; j < 4; j++) {
            const float bj = bias[co0 + 4 * tc + j];
            if constexpr (RPT == 4) {
                float4 o;
                o.x = acc[0][j] + bj; o.y = acc[1][j] + bj;
                o.z = acc[2][j] + bj; o.w = acc[3][j] + bj;
                if (RELU) {
                    o.x = fmaxf(o.x, 0.f); o.y = fmaxf(o.y, 0.f);
                    o.z = fmaxf(o.z, 0.f); o.w = fmaxf(o.w, 0.f);
                }
                *(float4*)(outT + (size_t)(co0 + 4 * tc + j) * LP + 4 * tr) = o;
            } else {
                float2 o;
                o.x = acc[0][j] + bj; o.y = acc[1][j] + bj;
                if (RELU) { o.x = fmaxf(o.x, 0.f); o.y = fmaxf(o.y, 0.f); }
                *(float2*)(outT + (size_t)(co0 + 4 * tc + j) * LP + 2 * tr) = o;
            }
        }
    }
}

template <int CIN, int COUT, int TT>
DEV void gemm_maxout(const float* __restrict__ inT, const float* __restrict__ W,
                     const float* __restrict__ bias, float* __restrict__ outg,
                     float (*wt)[64], float (*colred)[64], const int t, const int c) {
    constexpr int RPT = 1024 / TT;
    constexpr int NW  = TT / 64;
    constexpr int NCH = CIN / 32;   // CIN here is always a multiple of 32
    const int tc = t & 15, tr = t >> 4, wave = t >> 6;
    for (int co0 = 0; co0 < COUT; co0 += 64) {
        float acc[RPT][4] = {};
        for (int ch = 0; ch < NCH; ch++) {
            const int ci0 = ch * 32;
            __syncthreads();
            for (int e = t; e < 2048; e += TT) {
                const int co = e & 63, ci = e >> 6;
                wt[ci][co] = W[(size_t)(ci0 + ci) * COUT + co0 + co];
            }
            __syncthreads();
#pragma unroll 4
            for (int ci = 0; ci < 32; ci++)
                fma_step<RPT>(inT, (const float(*)[64])wt, ci0 + ci, ci, tr, tc, acc);
        }
        float vr[4];
#pragma unroll
        for (int j = 0; j < 4; j++) {
            const float bj = bias[co0 + 4 * tc + j];
            float m = -1e30f;  // same sentinel as reference mask
#pragma unroll
            for (int i = 0; i < RPT; i++) {
                const float v = acc[i][j] + bj;
                if (RPT * tr + i < c) m = fmaxf(m, v);
            }
            m = fmaxf(m, __shfl_xor(m, 16, 64));
            m = fmaxf(m, __shfl_xor(m, 32, 64));
            vr[j] = m;
        }
        if ((t & 48) == 0) {
#pragma unroll
            for (int j = 0; j < 4; j++) colred[wave][4 * tc + j] = vr[j];
        }
        __syncthreads();
        if (t < 64) {
            float m = colred[0][t];
#pragma unroll
            for (int w = 1; w < NW; w++) m = fmaxf(m, colred[w][t]);
            outg[co0 + t] = m;
        }
        __syncthreads();
    }
}

// =====================================================================================
// SA conv: one block per dst point. Gathers (x_j, rel) into LDS (rows>=count zeroed),
// 3-layer MLP, masked max over neighbors -> x_out[bs].
// =====================================================================================
template <int CX, int C0, int C1, int C2, int NSRC, int TT>
__global__ __launch_bounds__(TT) void sa_conv_kernel(
    const float* __restrict__ x_src, const float* __restrict__ pos_src,
    const float* __restrict__ pos_dst, const int* __restrict__ nidx,
    const int* __restrict__ ncnt,
    const float* __restrict__ w0, const float* __restrict__ b0,
    const float* __restrict__ w1, const float* __restrict__ b1,
    const float* __restrict__ w2, const float* __restrict__ b2,
    float* __restrict__ x_out, const int S) {
    constexpr int CIN = CX + 3;
    constexpr int AR  = (CIN > C1) ? CIN : C1;
    __shared__ float bufA[AR * LP];
    __shared__ float bufB[C0 * LP];
    __shared__ float wt[32][64];
    __shared__ float colred[TT / 64][64];
    const int bs = blockIdx.x, t = threadIdx.x;
    const int b = bs / S;
    const int c = ncnt[bs];
    const int* ni = nidx + (size_t)bs * 64;
    const float* pd = pos_dst + (size_t)bs * 3;
    const float qx = pd[0], qy = pd[1], qz = pd[2];
    if constexpr (CX > 0) {
        constexpr int LG = (CX == 256) ? 8 : 7;
#pragma unroll 4
        for (int e = t; e < 64 * CX; e += TT) {
            const int ci = e & (CX - 1), k = e >> LG;
            float v = 0.f;
            if (k < c) v = x_src[((size_t)b * NSRC + ni[k]) * CX + ci];
            bufA[(size_t)ci * LP + k] = v;
        }
    }
    for (int e = t; e < 192; e += TT) {
        const int k = e & 63, ci = e >> 6;
        float v = 0.f;
        if (k < c) {
            const float* pj = pos_src + ((size_t)b * NSRC + ni[k]) * 3;
            v = (ci == 0 ? pj[0] - qx : (ci == 1 ? pj[1] - qy : pj[2] - qz));
        }
        bufA[(size_t)(CX + ci) * LP + k] = v;
    }
    __syncthreads();
    gemm_tile<CIN, C0, true, TT>(bufA, w0, b0, bufB, wt, t);
    __syncthreads();
    gemm_tile<C0, C1, true, TT>(bufB, w1, b1, bufA, wt, t);
    __syncthreads();
    gemm_maxout<C1, C2, TT>(bufA, w2, b2, x_out + (size_t)bs * C2, wt, colred, t, c);
}

// =====================================================================================
// Global SA: layer 1 (515 -> 512, relu) to ws, layer 2 (512 -> 1024) + max over 64 pts.
// =====================================================================================
__global__ __launch_bounds__(256) void gsa1_kernel(const float* __restrict__ x3,
                                                   const float* __restrict__ pos3,
                                                   const float* __restrict__ w0,
                                                   const float* __restrict__ b0,
                                                   float* __restrict__ h1) {
    __shared__ float at[32][LP];
    __shared__ float wt[32][64];
    const int b = blockIdx.x >> 3, co0 = (blockIdx.x & 7) * 64;
    const int t = threadIdx.x, tc = t & 15, tr = t >> 4;
    float acc[4][4] = {};
    for (int ci0 = 0; ci0 < 515; ci0 += 32) {
        const int cc = (515 - ci0) < 32 ? (515 - ci0) : 32;
        __syncthreads();
        for (int e = t; e < cc * 64; e += 256) {
            const int k = e & 63, ci = e >> 6, cig = ci0 + ci;
            at[ci][k] = (cig < 512) ? x3[((size_t)b * 64 + k) * 512 + cig]
                                    : pos3[((size_t)b * 64 + k) * 3 + (cig - 512)];
        }
        for (int e = t; e < cc * 64; e += 256) {
            const int co = e & 63, ci = e >> 6;
            wt[ci][co] = w0[(size_t)(ci0 + ci) * 512 + co0 + co];
        }
        __syncthreads();
#pragma unroll 4
        for (int ci = 0; ci < 32; ci++) {
            if (ci >= cc) break;
            const float4 a = *(const float4*)&at[ci][4 * tr];
            const float4 w = *(const float4*)&wt[ci][4 * tc];
            const float av[4] = {a.x, a.y, a.z, a.w};
            const float wv[4] = {w.x, w.y, w.z, w.w};
#pragma unroll
            for (int i = 0; i < 4; i++)
#pragma unroll
                for (int j = 0; j < 4; j++) acc[i][j] = fmaf(av[i], wv[j], acc[i][j]);
        }
    }
#pragma unroll
    for (int j = 0; j < 4; j++) {
        const float bj = b0[co0 + 4 * tc + j];
#pragma unroll
        for (int i = 0; i < 4; i++) {
            float v = acc[i][j] + bj;
            v = fmaxf(v, 0.f);
            h1[((size_t)b * 64 + 4 * tr + i) * 512 + co0 + 4 * tc + j] = v;
        }
    }
}

__global__ __launch_bounds__(256) void gsa2_kernel(const float* __restrict__ h1,
                                                   const float* __restrict__ w1,
                                                   const float* __restrict__ b1,
                                                   float* __restrict__ out) {
    __shared__ float at[32][LP];
    __shared__ float wt[32][64];
    __shared__ float colred[4][64];
    const int b = blockIdx.x >> 4, co0 = (blockIdx.x & 15) * 64;
    const int t = threadIdx.x, tc = t & 15, tr = t >> 4, wave = t >> 6;
    float acc[4][4] = {};
    for (int ci0 = 0; ci0 < 512; ci0 += 32) {
        __syncthreads();
        for (int e = t; e < 32 * 64; e += 256) {
            const int k = e & 63, ci = e >> 6;
            at[ci][k] = h1[((size_t)b * 64 + k) * 512 + ci0 + ci];
        }
        for (int e = t; e < 32 * 64; e += 256) {
            const int co = e & 63, ci = e >> 6;
            wt[ci][co] = w1[(size_t)(ci0 + ci) * 1024 + co0 + co];
        }
        __syncthreads();
#pragma unroll 4
        for (int ci = 0; ci < 32; ci++) {
            const float4 a = *(const float4*)&at[ci][4 * tr];
            const float4 w = *(const float4*)&wt[ci][4 * tc];
            const float av[4] = {a.x, a.y, a.z, a.w};
            const float wv[4] = {w.x, w.y, w.z, w.w};
#pragma unroll
            for (int i = 0; i < 4; i++)
#pragma unroll
                for (int j = 0; j < 4; j++) acc[i][j] = fmaf(av[i], wv[j], acc[i][j]);
        }
    }
    float vr[4];
#pragma unroll
    for (int j = 0; j < 4; j++) {
        const float bj = b1[co0 + 4 * tc + j];
        float m = -1e30f;
#pragma unroll
        for (int i = 0; i < 4; i++) m = fmaxf(m, acc[i][j] + bj);
        m = fmaxf(m, __shfl_xor(m, 16, 64));
        m = fmaxf(m, __shfl_xor(m, 32, 64));
        vr[j] = m;
    }
    if ((t & 48) == 0) {
#pragma unroll
        for (int j = 0; j < 4; j++) colred[wave][4 * tc + j] = vr[j];
    }
    __syncthreads();
    if (t < 64) {
        const float m = fmaxf(fmaxf(colred[0][t], colred[1][t]),
                              fmaxf(colred[2][t], colred[3][t]));
        out[(size_t)b * 1024 + co0 + t] = m;
    }
}

// =====================================================================================
extern "C" void kernel_launch(void* const* d_in, const int* in_sizes, int n_in,
                              void* d_out, int out_size, void* d_ws, size_t ws_size,
                              hipStream_t stream) {
    (void)in_sizes; (void)n_in; (void)out_size; (void)ws_size;
    const float* pos    = (const float*)d_in[0];
    const float* sa1_w0 = (const float*)d_in[1];  const float* sa1_b0 = (const float*)d_in[2];
    const float* sa1_w1 = (const float*)d_in[3];  const float* sa1_b1 = (const float*)d_in[4];
    const float* sa1_w2 = (const float*)d_in[5];  const float* sa1_b2 = (const float*)d_in[6];
    const float* sa2_w0 = (const float*)d_in[7];  const float* sa2_b0 = (const float*)d_in[8];
    const float* sa2_w1 = (const float*)d_in[9];  const float* sa2_b1 = (const float*)d_in[10];
    const float* sa2_w2 = (const float*)d_in[11]; const float* sa2_b2 = (const float*)d_in[12];
    const float* sa3_w0 = (const float*)d_in[13]; const float* sa3_b0 = (const float*)d_in[14];
    const float* sa3_w1 = (const float*)d_in[15]; const float* sa3_b1 = (const float*)d_in[16];
    const float* sa3_w2 = (const float*)d_in[17]; const float* sa3_b2 = (const float*)d_in[18];
    const float* sa4_w0 = (const float*)d_in[19]; const float* sa4_b0 = (const float*)d_in[20];
    const float* sa4_w1 = (const float*)d_in[21]; const float* sa4_b1 = (const float*)d_in[22];
    float* out = (float*)d_out;
    char* ws = (char*)d_ws;

    float* pos1 = (float*)(ws + 0);         // [8,1024,3]
    float* pos2 = (float*)(ws + 98304);     // [8,256,3]
    float* pos3 = (float*)(ws + 122880);    // [8,64,3]
    float* x1   = (float*)(ws + 129024);    // [8,1024,128]
    float* x2   = (float*)(ws + 4323328);   // [8,256,256]
    float* x3   = (float*)(ws + 6420480);   // [8,64,512]
    int* nidx1  = (int*)(ws + 7469056);     // [8*1024,64]
    int* ncnt1  = (int*)(ws + 9566208);     // [8*1024]
    int* nidx2  = (int*)(ws + 9598976);     // [8*256,64]
    int* ncnt2  = (int*)(ws + 10123264);    // [8*256]
    int* nidx3  = (int*)(ws + 10131456);    // [8*64,64]
    int* ncnt3  = (int*)(ws + 10262528);    // [8*64]
    float* h1g  = (float*)(ws + 10264576);  // [8*64,512]

    const float rsq1 = (float)(0.2 * 0.2);
    const float rsq2 = (float)(0.4 * 0.4);
    const float rsq3 = (float)(0.8 * 0.8);

    fps_kernel<4096, 1024, 256><<<dim3(8), dim3(256), 0, stream>>>(pos, pos1);
    fps_kernel<1024, 256, 256><<<dim3(8), dim3(256), 0, stream>>>(pos1, pos2);
    fps_kernel<256, 64, 256><<<dim3(8), dim3(256), 0, stream>>>(pos2, pos3);

    ballq_kernel<4096, 256><<<dim3(8 * 1024), dim3(256), 0, stream>>>(pos, pos1, 1024, rsq1, nidx1, ncnt1);
    ballq_kernel<1024, 256><<<dim3(8 * 256), dim3(256), 0, stream>>>(pos1, pos2, 256, rsq2, nidx2, ncnt2);
    ballq_kernel<256, 256><<<dim3(8 * 64), dim3(256), 0, stream>>>(pos2, pos3, 64, rsq3, nidx3, ncnt3);

    sa_conv_kernel<0, 64, 64, 128, 4096, 256><<<dim3(8 * 1024), dim3(256), 0, stream>>>(
        nullptr, pos, pos1, nidx1, ncnt1, sa1_w0, sa1_b0, sa1_w1, sa1_b1, sa1_w2, sa1_b2, x1, 1024);
    sa_conv_kernel<128, 128, 128, 256, 1024, 256><<<dim3(8 * 256), dim3(256), 0, stream>>>(
        x1, pos1, pos2, nidx2, ncnt2, sa2_w0, sa2_b0, sa2_w1, sa2_b1, sa2_w2, sa2_b2, x2, 256);
    sa_conv_kernel<256, 256, 256, 512, 256, 512><<<dim3(8 * 64), dim3(512), 0, stream>>>(
        x2, pos2, pos3, nidx3, ncnt3, sa3_w0, sa3_b0, sa3_w1, sa3_b1, sa3_w2, sa3_b2, x3, 64);

    gsa1_kernel<<<dim3(64), dim3(256), 0, stream>>>(x3, pos3, sa4_w0, sa4_b0, h1g);
    gsa2_kernel<<<dim3(128), dim3(256), 0, stream>>>(h1g, sa4_w1, sa4_b1, out);
}

// Round 5
// 1798.462 us; speedup vs baseline: 2.5746x; 1.0656x over previous
//
#include <hip/hip_runtime.h>

#define DEV __device__ __forceinline__

// ---------- exact (non-contracted) squared distance: matches jnp sum(((a-b)**2), -1) ----------
DEV float d2_exact(float ax, float ay, float az, float bx, float by, float bz) {
    float dx = __fadd_rn(ax, -bx);
    float dy = __fadd_rn(ay, -by);
    float dz = __fadd_rn(az, -bz);
    return __fadd_rn(__fadd_rn(__fmul_rn(dx, dx), __fmul_rn(dy, dy)), __fmul_rn(dz, dz));
}

DEV unsigned long long umax64(unsigned long long a, unsigned long long b) { return a > b ? a : b; }
DEV unsigned long long umin64(unsigned long long a, unsigned long long b) { return a < b ? a : b; }

// ---------- DPP wave64 max (VALU-only, no LDS): result broadcast via readlane ----------
template <int CTRL>
DEV float dpp_fmax(float x) {
    const int xi = __float_as_int(x);
    const int yi = __builtin_amdgcn_update_dpp(xi, xi, CTRL, 0xF, 0xF, false);
    return fmaxf(x, __int_as_float(yi));
}

DEV float wave_fmax_bcast(float x) {
    x = dpp_fmax<0x111>(x);  // row_shr:1
    x = dpp_fmax<0x112>(x);  // row_shr:2
    x = dpp_fmax<0x114>(x);  // row_shr:4
    x = dpp_fmax<0x118>(x);  // row_shr:8
    x = dpp_fmax<0x142>(x);  // row_bcast:15
    x = dpp_fmax<0x143>(x);  // row_bcast:31  -> lane63 holds wave max
    return __int_as_float(__builtin_amdgcn_readlane(__float_as_int(x), 63));
}

// =====================================================================================
// FPS: one block per batch. pos [B,N,3] -> pos_out [B,S,3]. Deterministic start idx 0.
// Per-iter: per-thread argmax over contiguous chunk (strict > = lowest idx on tie),
// DPP value-max + ballot/ffs/readlane for the index (all VALU/SALU), ONE barrier,
// all waves redundantly reduce the NW packed keys. Matches jnp.argmax tie-break.
// =====================================================================================
template <int N, int S, int T>
__global__ __launch_bounds__(T) void fps_kernel(const float* __restrict__ pos,
                                                float* __restrict__ pos_out) {
    constexpr int C  = N / T;
    constexpr int NW = T / 64;
    __shared__ float sx[N], sy[N], sz[N];
    __shared__ unsigned long long sred[2][NW];
    const int b = blockIdx.x, t = threadIdx.x;
    const float* p = pos + (size_t)b * N * 3;
    for (int i = t; i < N; i += T) { sx[i] = p[3*i]; sy[i] = p[3*i+1]; sz[i] = p[3*i+2]; }
    __syncthreads();
    float px[C], py[C], pz[C], md[C];
    const int base = t * C;
#pragma unroll
    for (int i = 0; i < C; i++) { px[i]=sx[base+i]; py[i]=sy[base+i]; pz[i]=sz[base+i]; md[i]=1e30f; }
    float cx = sx[0], cy = sy[0], cz = sz[0];
    const int lane = t & 63, wave = t >> 6;
    for (int s = 0; s < S; s++) {
        if (t == 0) {
            float* po = pos_out + ((size_t)b * S + s) * 3;
            po[0] = cx; po[1] = cy; po[2] = cz;
        }
        float bv = -1.0f; int bi = 0;
#pragma unroll
        for (int i = 0; i < C; i++) {
            float d = d2_exact(px[i], py[i], pz[i], cx, cy, cz);
            float m = fminf(md[i], d);
            md[i] = m;
            if (m > bv) { bv = m; bi = base + i; }   // strict > keeps first max in chunk
        }
        const float wm = wave_fmax_bcast(bv);             // wave max, broadcast (SGPR)
        const unsigned long long eq = __ballot(bv == wm); // lanes holding the max
        const int srcl = __ffsll(eq) - 1;                 // lowest lane = lowest index
        const int wbi  = __builtin_amdgcn_readlane(bi, srcl);
        if (lane == 0)
            sred[s & 1][wave] = ((unsigned long long)__float_as_uint(wm) << 32) |
                                (unsigned long long)(unsigned int)(~wbi);
        __syncthreads();
        unsigned long long v = sred[s & 1][0];
#pragma unroll
        for (int w = 1; w < NW; w++) v = umax64(v, sred[s & 1][w]);
        const int cur = (int)(~(unsigned int)v);
        cx = sx[cur]; cy = sy[cur]; cz = sz[cur];
    }
}

// =====================================================================================
// Ball query: one block per (b,s). Emits the neighbor SET (order-free when count<=K,
// exact top-K extraction with lowest-index ties when count>K).
// =====================================================================================
template <int NSRC, int T>
__global__ __launch_bounds__(T) void ballq_kernel(const float* __restrict__ pos_src,
                                                  const float* __restrict__ pos_dst,
                                                  const int S, const float rsq,
                                                  int* __restrict__ nidx, int* __restrict__ ncnt) {
    __shared__ float d2s[NSRC];
    __shared__ int scnt, sfill;
    __shared__ unsigned long long sred[T / 64];
    const int bs = blockIdx.x, t = threadIdx.x;
    const int b = bs / S;
    const float* pd = pos_dst + (size_t)bs * 3;
    const float qx = pd[0], qy = pd[1], qz = pd[2];
    const float* ps = pos_src + (size_t)b * NSRC * 3;
    if (t == 0) { scnt = 0; sfill = 0; }
    __syncthreads();
    int lc = 0;
    for (int j = t; j < NSRC; j += T) {
        float d2 = d2_exact(ps[3*j], ps[3*j+1], ps[3*j+2], qx, qy, qz);
        d2s[j] = d2;
        lc += (d2 < rsq) ? 1 : 0;
    }
    if (lc) atomicAdd(&scnt, lc);
    __syncthreads();
    const int c = scnt;
    int* mi = nidx + (size_t)bs * 64;
    if (c <= 64) {
        if (t == 0) ncnt[bs] = c;
        for (int j = t; j < NSRC; j += T) {
            if (d2s[j] < rsq) { int p = atomicAdd(&sfill, 1); mi[p] = j; }
        }
    } else {
        if (t == 0) ncnt[bs] = 64;
        const int lane = t & 63, wave = t >> 6;
        for (int k = 0; k < 64; k++) {
            unsigned long long best = ~0ULL;
            for (int j = t; j < NSRC; j += T) {
                unsigned long long key =
                    ((unsigned long long)__float_as_uint(d2s[j]) << 32) | (unsigned int)j;
                best = umin64(best, key);
            }
#pragma unroll
            for (int o = 32; o >= 1; o >>= 1) best = umin64(best, __shfl_xor(best, o, 64));
            if (lane == 0) sred[wave] = best;
            __syncthreads();
            if (t == 0) {
                unsigned long long v = sred[0];
                for (int w = 1; w < T / 64; w++) v = umin64(v, sred[w]);
                int j = (int)(unsigned int)v;
                mi[k] = j;
                d2s[j] = __uint_as_float(0x7F800000u);  // +inf: exclude from later picks
            }
            __syncthreads();
        }
    }
}

// =====================================================================================
// SA conv, lane=row design. rows (neighbors) = 64 = lanes of a wave; each wave owns 16
// output cols with acc[16] in VGPRs. Weight operand W[ci][co] is wave-uniform ->
// scalar loads (SGPR FMA operand), NO LDS traffic for weights, no staging barriers.
// Activations in LDS at row stride 65 floats: ds_read_b32 per (ci) per lane,
// conflict-free both for lane-indexed reads and ci-indexed gather writes.
// Accumulation order (ci ascending) identical to reference -> bitwise-stable.
// =====================================================================================
#define AST 65

template <int CIN, int COUT, bool RELU, int TT>
DEV void layer_fc(const float* __restrict__ inA, const float* __restrict__ W,
                  const float* __restrict__ bias, float* __restrict__ outA,
                  const int wav, const int lane) {
    constexpr int PASS = (TT / 64) * 16;
    for (int cb0 = 0; cb0 < COUT; cb0 += PASS) {
        const int cb = cb0 + wav * 16;
        const float* __restrict__ wp = W + cb;
        float acc[16] = {};
        int ci = 0;
        for (; ci + 4 <= CIN; ci += 4) {
            const float a0 = inA[(ci + 0) * AST + lane];
            const float a1 = inA[(ci + 1) * AST + lane];
            const float a2 = inA[(ci + 2) * AST + lane];
            const float a3 = inA[(ci + 3) * AST + lane];
#pragma unroll
            for (int j = 0; j < 16; j++) acc[j] = fmaf(a0, wp[(size_t)(ci + 0) * COUT + j], acc[j]);
#pragma unroll
            for (int j = 0; j < 16; j++) acc[j] = fmaf(a1, wp[(size_t)(ci + 1) * COUT + j], acc[j]);
#pragma unroll
            for (int j = 0; j < 16; j++) acc[j] = fmaf(a2, wp[(size_t)(ci + 2) * COUT + j], acc[j]);
#pragma unroll
            for (int j = 0; j < 16; j++) acc[j] = fmaf(a3, wp[(size_t)(ci + 3) * COUT + j], acc[j]);
        }
        for (; ci < CIN; ci++) {
            const float a0 = inA[ci * AST + lane];
#pragma unroll
            for (int j = 0; j < 16; j++) acc[j] = fmaf(a0, wp[(size_t)ci * COUT + j], acc[j]);
        }
#pragma unroll
        for (int j = 0; j < 16; j++) {
            float v = acc[j] + bias[cb + j];
            if (RELU) v = fmaxf(v, 0.f);
            outA[(size_t)(cb + j) * AST + lane] = v;
        }
    }
}

template <int CIN, int COUT, int TT>
DEV void layer_max(const float* __restrict__ inA, const float* __restrict__ W,
                   const float* __restrict__ bias, float* __restrict__ outg,
                   const int wav, const int lane, const int c) {
    constexpr int PASS = (TT / 64) * 16;
    for (int cb0 = 0; cb0 < COUT; cb0 += PASS) {
        const int cb = cb0 + wav * 16;
        const float* __restrict__ wp = W + cb;
        float acc[16] = {};
        int ci = 0;
        for (; ci + 4 <= CIN; ci += 4) {
            const float a0 = inA[(ci + 0) * AST + lane];
            const float a1 = inA[(ci + 1) * AST + lane];
            const float a2 = inA[(ci + 2) * AST + lane];
            const float a3 = inA[(ci + 3) * AST + lane];
#pragma unroll
            for (int j = 0; j < 16; j++) acc[j] = fmaf(a0, wp[(size_t)(ci + 0) * COUT + j], acc[j]);
#pragma unroll
            for (int j = 0; j < 16; j++) acc[j] = fmaf(a1, wp[(size_t)(ci + 1) * COUT + j], acc[j]);
#pragma unroll
            for (int j = 0; j < 16; j++) acc[j] = fmaf(a2, wp[(size_t)(ci + 2) * COUT + j], acc[j]);
#pragma unroll
            for (int j = 0; j < 16; j++) acc[j] = fmaf(a3, wp[(size_t)(ci + 3) * COUT + j], acc[j]);
        }
        for (; ci < CIN; ci++) {
            const float a0 = inA[ci * AST + lane];
#pragma unroll
            for (int j = 0; j < 16; j++) acc[j] = fmaf(a0, wp[(size_t)ci * COUT + j], acc[j]);
        }
        float vout = 0.f;
#pragma unroll
        for (int j = 0; j < 16; j++) {
            const float v = (lane < c) ? acc[j] + bias[cb + j] : -1e30f;  // reference mask
            const float m = wave_fmax_bcast(v);
            if (lane == j) vout = m;
        }
        if (lane < 16) outg[cb + lane] = vout;
    }
}

template <int CX, int C0, int C1, int C2, int NSRC, int TT>
__global__ __launch_bounds__(TT) void sa_conv_kernel(
    const float* __restrict__ x_src, const float* __restrict__ pos_src,
    const float* __restrict__ pos_dst, const int* __restrict__ nidx,
    const int* __restrict__ ncnt,
    const float* __restrict__ w0, const float* __restrict__ b0,
    const float* __restrict__ w1, const float* __restrict__ b1,
    const float* __restrict__ w2, const float* __restrict__ b2,
    float* __restrict__ x_out, const int S) {
    constexpr int CIN = CX + 3;
    constexpr int AR  = (CIN > C1) ? CIN : C1;
    __shared__ float bufA[AR * AST];
    __shared__ float bufB[C0 * AST];
    __shared__ int sni[64];
    const int bs = blockIdx.x, t = threadIdx.x;
    const int b = bs / S;
    const int c = ncnt[bs];
    const float* pd = pos_dst + (size_t)bs * 3;
    const float qx = pd[0], qy = pd[1], qz = pd[2];
    if (t < 64) sni[t] = nidx[(size_t)bs * 64 + t];
    __syncthreads();
    if constexpr (CX > 0) {
        constexpr int LG = (CX == 256) ? 8 : 7;
        for (int e = t; e < 64 * CX; e += TT) {
            const int ci = e & (CX - 1), k = e >> LG;
            float v = 0.f;
            if (k < c) v = x_src[((size_t)b * NSRC + sni[k]) * CX + ci];
            bufA[ci * AST + k] = v;
        }
    }
    for (int e = t; e < 192; e += TT) {
        const int k = e & 63, ci = e >> 6;
        float v = 0.f;
        if (k < c) {
            const float* pj = pos_src + ((size_t)b * NSRC + sni[k]) * 3;
            v = (ci == 0 ? pj[0] - qx : (ci == 1 ? pj[1] - qy : pj[2] - qz));
        }
        bufA[(CX + ci) * AST + k] = v;
    }
    __syncthreads();
    const int wav  = __builtin_amdgcn_readfirstlane(t >> 6);
    const int lane = t & 63;
    layer_fc<CIN, C0, true, TT>(bufA, w0, b0, bufB, wav, lane);
    __syncthreads();
    layer_fc<C0, C1, true, TT>(bufB, w1, b1, bufA, wav, lane);
    __syncthreads();
    layer_max<C1, C2, TT>(bufA, w2, b2, x_out + (size_t)bs * C2, wav, lane, c);
}

// =====================================================================================
// Global SA: layer 1 (515 -> 512, relu) to ws, layer 2 (512 -> 1024) + max over 64 pts.
// (small: ~64/128 blocks; kept in the proven 4x4-tile form)
// =====================================================================================
#define LP 68

__global__ __launch_bounds__(256) void gsa1_kernel(const float* __restrict__ x3,
                                                   const float* __restrict__ pos3,
                                                   const float* __restrict__ w0,
                                                   const float* __restrict__ b0,
                                                   float* __restrict__ h1) {
    __shared__ float at[32][LP];
    __shared__ float wt[32][64];
    const int b = blockIdx.x >> 3, co0 = (blockIdx.x & 7) * 64;
    const int t = threadIdx.x, tc = t & 15, tr = t >> 4;
    float acc[4][4] = {};
    for (int ci0 = 0; ci0 < 515; ci0 += 32) {
        const int cc = (515 - ci0) < 32 ? (515 - ci0) : 32;
        __syncthreads();
        for (int e = t; e < cc * 64; e += 256) {
            const int k = e & 63, ci = e >> 6, cig = ci0 + ci;
            at[ci][k] = (cig < 512) ? x3[((size_t)b * 64 + k) * 512 + cig]
                                    : pos3[((size_t)b * 64 + k) * 3 + (cig - 512)];
        }
        for (int e = t; e < cc * 64; e += 256) {
            const int co = e & 63, ci = e >> 6;
            wt[ci][co] = w0[(size_t)(ci0 + ci) * 512 + co0 + co];
        }
        __syncthreads();
#pragma unroll 4
        for (int ci = 0; ci < 32; ci++) {
            if (ci >= cc) break;
            const float4 a = *(const float4*)&at[ci][4 * tr];
            const float4 w = *(const float4*)&wt[ci][4 * tc];
            const float av[4] = {a.x, a.y, a.z, a.w};
            const float wv[4] = {w.x, w.y, w.z, w.w};
#pragma unroll
            for (int i = 0; i < 4; i++)
#pragma unroll
                for (int j = 0; j < 4; j++) acc[i][j] = fmaf(av[i], wv[j], acc[i][j]);
        }
    }
#pragma unroll
    for (int j = 0; j < 4; j++) {
        const float bj = b0[co0 + 4 * tc + j];
#pragma unroll
        for (int i = 0; i < 4; i++) {
            float v = acc[i][j] + bj;
            v = fmaxf(v, 0.f);
            h1[((size_t)b * 64 + 4 * tr + i) * 512 + co0 + 4 * tc + j] = v;
        }
    }
}

__global__ __launch_bounds__(256) void gsa2_kernel(const float* __restrict__ h1,
                                                   const float* __restrict__ w1,
                                                   const float* __restrict__ b1,
                                                   float* __restrict__ out) {
    __shared__ float at[32][LP];
    __shared__ float wt[32][64];
    __shared__ float colred[4][64];
    const int b = blockIdx.x >> 4, co0 = (blockIdx.x & 15) * 64;
    const int t = threadIdx.x, tc = t & 15, tr = t >> 4, wave = t >> 6;
    float acc[4][4] = {};
    for (int ci0 = 0; ci0 < 512; ci0 += 32) {
        __syncthreads();
        for (int e = t; e < 32 * 64; e += 256) {
            const int k = e & 63, ci = e >> 6;
            at[ci][k] = h1[((size_t)b * 64 + k) * 512 + ci0 + ci];
        }
        for (int e = t; e < 32 * 64; e += 256) {
            const int co = e & 63, ci = e >> 6;
            wt[ci][co] = w1[(size_t)(ci0 + ci) * 1024 + co0 + co];
        }
        __syncthreads();
#pragma unroll 4
        for (int ci = 0; ci < 32; ci++) {
            const float4 a = *(const float4*)&at[ci][4 * tr];
            const float4 w = *(const float4*)&wt[ci][4 * tc];
            const float av[4] = {a.x, a.y, a.z, a.w};
            const float wv[4] = {w.x, w.y, w.z, w.w};
#pragma unroll
            for (int i = 0; i < 4; i++)
#pragma unroll
                for (int j = 0; j < 4; j++) acc[i][j] = fmaf(av[i], wv[j], acc[i][j]);
        }
    }
    float vr[4];
#pragma unroll
    for (int j = 0; j < 4; j++) {
        const float bj = b1[co0 + 4 * tc + j];
        float m = -1e30f;
#pragma unroll
        for (int i = 0; i < 4; i++) m = fmaxf(m, acc[i][j] + bj);
        m = fmaxf(m, __shfl_xor(m, 16, 64));
        m = fmaxf(m, __shfl_xor(m, 32, 64));
        vr[j] = m;
    }
    if ((t & 48) == 0) {
#pragma unroll
        for (int j = 0; j < 4; j++) colred[wave][4 * tc + j] = vr[j];
    }
    __syncthreads();
    if (t < 64) {
        const float m = fmaxf(fmaxf(colred[0][t], colred[1][t]),
                              fmaxf(colred[2][t], colred[3][t]));
        out[(size_t)b * 1024 + co0 + t] = m;
    }
}

// =====================================================================================
extern "C" void kernel_launch(void* const* d_in, const int* in_sizes, int n_in,
                              void* d_out, int out_size, void* d_ws, size_t ws_size,
                              hipStream_t stream) {
    (void)in_sizes; (void)n_in; (void)out_size; (void)ws_size;
    const float* pos    = (const float*)d_in[0];
    const float* sa1_w0 = (const float*)d_in[1];  const float* sa1_b0 = (const float*)d_in[2];
    const float* sa1_w1 = (const float*)d_in[3];  const float* sa1_b1 = (const float*)d_in[4];
    const float* sa1_w2 = (const float*)d_in[5];  const float* sa1_b2 = (const float*)d_in[6];
    const float* sa2_w0 = (const float*)d_in[7];  const float* sa2_b0 = (const float*)d_in[8];
    const float* sa2_w1 = (const float*)d_in[9];  const float* sa2_b1 = (const float*)d_in[10];
    const float* sa2_w2 = (const float*)d_in[11]; const float* sa2_b2 = (const float*)d_in[12];
    const float* sa3_w0 = (const float*)d_in[13]; const float* sa3_b0 = (const float*)d_in[14];
    const float* sa3_w1 = (const float*)d_in[15]; const float* sa3_b1 = (const float*)d_in[16];
    const float* sa3_w2 = (const float*)d_in[17]; const float* sa3_b2 = (const float*)d_in[18];
    const float* sa4_w0 = (const float*)d_in[19]; const float* sa4_b0 = (const float*)d_in[20];
    const float* sa4_w1 = (const float*)d_in[21]; const float* sa4_b1 = (const float*)d_in[22];
    float* out = (float*)d_out;
    char* ws = (char*)d_ws;

    float* pos1 = (float*)(ws + 0);         // [8,1024,3]
    float* pos2 = (float*)(ws + 98304);     // [8,256,3]
    float* pos3 = (float*)(ws + 122880);    // [8,64,3]
    float* x1   = (float*)(ws + 129024);    // [8,1024,128]
    float* x2   = (float*)(ws + 4323328);   // [8,256,256]
    float* x3   = (float*)(ws + 6420480);   // [8,64,512]
    int* nidx1  = (int*)(ws + 7469056);     // [8*1024,64]
    int* ncnt1  = (int*)(ws + 9566208);     // [8*1024]
    int* nidx2  = (int*)(ws + 9598976);     // [8*256,64]
    int* ncnt2  = (int*)(ws + 10123264);    // [8*256]
    int* nidx3  = (int*)(ws + 10131456);    // [8*64,64]
    int* ncnt3  = (int*)(ws + 10262528);    // [8*64]
    float* h1g  = (float*)(ws + 10264576);  // [8*64,512]

    const float rsq1 = (float)(0.2 * 0.2);
    const float rsq2 = (float)(0.4 * 0.4);
    const float rsq3 = (float)(0.8 * 0.8);

    fps_kernel<4096, 1024, 256><<<dim3(8), dim3(256), 0, stream>>>(pos, pos1);
    fps_kernel<1024, 256, 256><<<dim3(8), dim3(256), 0, stream>>>(pos1, pos2);
    fps_kernel<256, 64, 256><<<dim3(8), dim3(256), 0, stream>>>(pos2, pos3);

    ballq_kernel<4096, 256><<<dim3(8 * 1024), dim3(256), 0, stream>>>(pos, pos1, 1024, rsq1, nidx1, ncnt1);
    ballq_kernel<1024, 256><<<dim3(8 * 256), dim3(256), 0, stream>>>(pos1, pos2, 256, rsq2, nidx2, ncnt2);
    ballq_kernel<256, 256><<<dim3(8 * 64), dim3(256), 0, stream>>>(pos2, pos3, 64, rsq3, nidx3, ncnt3);

    sa_conv_kernel<0, 64, 64, 128, 4096, 256><<<dim3(8 * 1024), dim3(256), 0, stream>>>(
        nullptr, pos, pos1, nidx1, ncnt1, sa1_w0, sa1_b0, sa1_w1, sa1_b1, sa1_w2, sa1_b2, x1, 1024);
    sa_conv_kernel<128, 128, 128, 256, 1024, 256><<<dim3(8 * 256), dim3(256), 0, stream>>>(
        x1, pos1, pos2, nidx2, ncnt2, sa2_w0, sa2_b0, sa2_w1, sa2_b1, sa2_w2, sa2_b2, x2, 256);
    sa_conv_kernel<256, 256, 256, 512, 256, 512><<<dim3(8 * 64), dim3(512), 0, stream>>>(
        x2, pos2, pos3, nidx3, ncnt3, sa3_w0, sa3_b0, sa3_w1, sa3_b1, sa3_w2, sa3_b2, x3, 64);

    gsa1_kernel<<<dim3(64), dim3(256), 0, stream>>>(x3, pos3, sa4_w0, sa4_b0, h1g);
    gsa2_kernel<<<dim3(128), dim3(256), 0, stream>>>(h1g, sa4_w1, sa4_b1, out);
}